// Round 21
// baseline (2653.178 us; speedup 1.0000x reference)
//
#include <hip/hip_runtime.h>
#include <hip/hip_fp16.h>
#include <stdint.h>

// ---------------- static problem config ----------------
#define S_TOT 21504
#define M_TOK 86016
// levels: (32,32) start 0, (64,64) start 1024, (128,128) start 5120

typedef __attribute__((ext_vector_type(8))) short bf16x8;
typedef __attribute__((ext_vector_type(4))) float f32x4;
typedef __attribute__((ext_vector_type(2))) float f32x2;

__device__ __forceinline__ unsigned short f2b(float f) {
  union { float f; unsigned u; } v; v.f = f;
  unsigned r = v.u + 0x7FFFu + ((v.u >> 16) & 1u);
  return (unsigned short)(r >> 16);
}
__device__ __forceinline__ unsigned short f2h(float f) {
  __half h = __float2half(f);
  return __half_as_ushort(h);
}
__device__ __forceinline__ float b2f(unsigned short h) {
  union { unsigned u; float f; } v; v.u = ((unsigned)h) << 16;
  return v.f;
}
__device__ __forceinline__ float blo(unsigned u) {
  union { unsigned u; float f; } v; v.u = u << 16; return v.f;
}
__device__ __forceinline__ float bhi(unsigned u) {
  union { unsigned u; float f; } v; v.u = u & 0xffff0000u; return v.f;
}
// fp16 pair access; (float)h folds into v_fma_mix_f32 at the consuming fma
__device__ __forceinline__ float h2lo(unsigned u) {
  union { unsigned u; __half2 h; } v; v.u = u; return __half2float(v.h.x);
}
__device__ __forceinline__ float h2hi(unsigned u) {
  union { unsigned u; __half2 h; } v; v.u = u; return __half2float(v.h.y);
}

// ---------------- bf16 MFMA GEMM: C = A * Bt^T + bias ----------------
// BM=BN=128, XCD-swizzled 1D grid, coalesced C via LDS bounce, double-buffered LDS
// with one barrier per 32-K step (round-20 K-loop, kept).
// NEW: 8 waves x (32x64) tiles, 512 threads. Per-wave acc halves (2x4 f32x4 = 32 VGPR)
// -> ~2x resident waves/SIMD for latency hiding (the one axis never varied; all
// intra-wave schedule variants were null because ~3 waves/SIMD cannot hide latency).
#define LSTR 40
#define TSZ (128 * LSTR)
template <int RELU, int OUTH>
__global__ __launch_bounds__(512) void gemm_kernel(
    const unsigned short* __restrict__ A, const unsigned short* __restrict__ Bt,
    const float* __restrict__ bias, const float* __restrict__ bias2, int nsplit,
    unsigned short* __restrict__ C, int N, int K, int ntx) {
  __shared__ unsigned short smem[4 * TSZ];  // [A0 | A1 | B0 | B1], 40 KB
  const int tid = threadIdx.x;
  const int wave = tid >> 6, lane = tid & 63;
  const int nblk = gridDim.x, chunk = nblk >> 3;
  const int bid = blockIdx.x;
  const int swz = (bid & 7) * chunk + (bid >> 3);
  const long m0 = (long)(swz / ntx) * 128;
  const int n0 = (swz % ntx) * 128;
  const int wm = (wave >> 1) * 32, wn = (wave & 1) * 64;  // 4x2 waves of 32x64
  const int l15 = lane & 15;

  f32x4 acc[2][4];
#pragma unroll
  for (int i = 0; i < 2; i++)
#pragma unroll
    for (int j = 0; j < 4; j++) acc[i][j] = (f32x4){0.f, 0.f, 0.f, 0.f};

  // staging: 512 threads cover the 512 16B-chunks of each 128x32 tile exactly once.
  const int ar = tid >> 2, ak = (tid & 3) * 8;
  int brA = n0 + ar; if (brA >= N) brA = N - 1;  // clamp OOB weight rows
  const unsigned short* a0p = A + (m0 + ar) * (long)K + ak;
  const unsigned short* b0p = Bt + (long)brA * K + ak;
  const int wo = ar * LSTR + ak;

  uint4 ra = *(const uint4*)a0p;
  uint4 rb = *(const uint4*)b0p;
  *(uint4*)(smem + wo) = ra;
  *(uint4*)(smem + 2 * TSZ + wo) = rb;
  if (32 < K) {
    ra = *(const uint4*)(a0p + 32);
    rb = *(const uint4*)(b0p + 32);
  }
  __syncthreads();

#define GEMM_COMPUTE(P)                                                               \
  {                                                                                   \
    const int kk = (lane >> 4) * 8;                                                   \
    const unsigned short* Ab = smem + (P)*TSZ;                                        \
    const unsigned short* Bb = smem + (2 + (P)) * TSZ;                                \
    bf16x8 af[2], bq[4];                                                              \
    _Pragma("unroll") for (int i = 0; i < 2; i++)                                     \
        af[i] = *(const bf16x8*)&Ab[(wm + i * 16 + l15) * LSTR + kk];                 \
    _Pragma("unroll") for (int j = 0; j < 4; j++)                                     \
        bq[j] = *(const bf16x8*)&Bb[(wn + j * 16 + l15) * LSTR + kk];                 \
    _Pragma("unroll") for (int i = 0; i < 2; i++)                                     \
        _Pragma("unroll") for (int j = 0; j < 4; j++)                                 \
            acc[i][j] = __builtin_amdgcn_mfma_f32_16x16x32_bf16(af[i], bq[j],         \
                                                                acc[i][j], 0, 0, 0); \
  }

  for (int k0 = 0; k0 < K; k0 += 64) {
    if (k0 + 32 < K) {  // stage tile+1 into buf1, refill regs for tile+2
      *(uint4*)(smem + TSZ + wo) = ra;
      *(uint4*)(smem + 3 * TSZ + wo) = rb;
      if (k0 + 64 < K) {
        ra = *(const uint4*)(a0p + k0 + 64);
        rb = *(const uint4*)(b0p + k0 + 64);
      }
    }
    GEMM_COMPUTE(0);
    __syncthreads();
    if (k0 + 64 < K) {
      *(uint4*)(smem + wo) = ra;
      *(uint4*)(smem + 2 * TSZ + wo) = rb;
      if (k0 + 96 < K) {
        ra = *(const uint4*)(a0p + k0 + 96);
        rb = *(const uint4*)(b0p + k0 + 96);
      }
    }
    GEMM_COMPUTE(1);
    __syncthreads();
  }
#undef GEMM_COMPUTE

  // coalesced C-write via LDS bounce (64 rows x 136 stride)
  unsigned short* stage = smem;
  const int colb = l15, rowb = ((lane >> 4) & 3) * 4;
#pragma unroll
  for (int half = 0; half < 2; half++) {
    __syncthreads();
    if ((wm >> 6) == half) {
      const int srow0 = wm & 63;
#pragma unroll
      for (int j = 0; j < 4; j++) {
        const int n = n0 + wn + j * 16 + colb;
        const float bn = (n < N) ? ((n < nsplit) ? bias[n] : bias2[n - nsplit]) : 0.f;
#pragma unroll
        for (int i = 0; i < 2; i++) {
#pragma unroll
          for (int r = 0; r < 4; r++) {
            float v = acc[i][j][r] + bn;
            if (RELU) v = fmaxf(v, 0.f);
            stage[(srow0 + i * 16 + rowb + r) * 136 + wn + j * 16 + colb] = OUTH ? f2h(v) : f2b(v);
          }
        }
      }
    }
    __syncthreads();
#pragma unroll
    for (int t = 0; t < 2; t++) {
      const int idx = t * 512 + tid;
      const int rr = idx >> 4;
      const int cc = (idx & 15) * 8;
      const int n = n0 + cc;
      if (n < N) {  // N % 8 == 0 -> whole chunk valid
        const long m = m0 + half * 64 + rr;
        *(uint4*)(C + m * N + n) = *(const uint4*)(stage + rr * 136 + cc);
      }
    }
  }
}

// ---------------- weight transpose + bf16 convert: [L][K][N] -> [L][N][K] ----------------
__global__ void wtrans_kernel(const float* __restrict__ src, unsigned short* __restrict__ dst,
                              int K, int N, size_t src_lstride, size_t dst_lstride) {
  __shared__ float t[32][33];
  const int tx = threadIdx.x, ty = threadIdx.y;
  const int n0 = blockIdx.x * 32, k0 = blockIdx.y * 32, l = blockIdx.z;
  src += (size_t)l * src_lstride;
  dst += (size_t)l * dst_lstride;
#pragma unroll
  for (int i = 0; i < 4; i++) t[ty * 4 + i][tx] = src[(size_t)(k0 + ty * 4 + i) * N + n0 + tx];
  __syncthreads();
#pragma unroll
  for (int i = 0; i < 4; i++)
    dst[(size_t)(n0 + ty * 4 + i) * K + k0 + tx] = f2b(t[tx][ty * 4 + i]);
}

// ---------------- flatten [B,C,H,W] -> [B,HW,C]; writes residual b16, pos b16, q b16 ----
__global__ void flatten_kernel(const float* __restrict__ src, const float* __restrict__ pos,
                               const float* __restrict__ lemb,
                               unsigned short* __restrict__ outb, unsigned short* __restrict__ posb,
                               unsigned short* __restrict__ qb, int HW, int s0) {
  __shared__ float ts[32][33];
  __shared__ float tp[32][33];
  const int tx = threadIdx.x, ty = threadIdx.y;
  const int hw0 = blockIdx.x * 32, c0 = blockIdx.y * 32, b = blockIdx.z;
  const size_t ibase = ((size_t)b * 256 + c0) * HW + hw0;
#pragma unroll
  for (int i = 0; i < 4; i++) {
    ts[ty * 4 + i][tx] = src[ibase + (size_t)(ty * 4 + i) * HW + tx];
    tp[ty * 4 + i][tx] = pos[ibase + (size_t)(ty * 4 + i) * HW + tx];
  }
  __syncthreads();
#pragma unroll
  for (int i = 0; i < 4; i++) {
    const int sI = s0 + hw0 + ty * 4 + i, c = c0 + tx;
    const size_t o = ((size_t)b * S_TOT + sI) * 256 + c;
    const float sv = ts[tx][ty * 4 + i];
    const unsigned short pb = f2b(tp[tx][ty * 4 + i] + lemb[c]);
    outb[o] = f2b(sv);
    posb[o] = pb;
    qb[o] = f2b(sv + b2f(pb));
  }
}

// ---------------- deformable attention sampling (fp16 value; oa = [offs(192)|aw(96)]) ----
// No inter-wave barriers: law/didx/dwt slices are wave-private.
__global__ __launch_bounds__(256) void deform_kernel(const unsigned short* __restrict__ value,
                                                     const unsigned short* __restrict__ oa,
                                                     unsigned short* __restrict__ attn) {
  __shared__ float law[4][96];
  __shared__ uint4 didx[4][96];
  __shared__ float4 dwt[4][96];
  const int tid = threadIdx.x;
  const int wv = tid >> 6, lane = tid & 63;
  const int bs = blockIdx.x * 4 + wv;
  const int b = bs / S_TOT, s = bs - b * S_TOT;

  if (lane < 8) {  // per-head softmax over NL*NP=12
    const unsigned short* ap = oa + (size_t)bs * 288 + 192 + lane * 12;
    const uint2 p0 = *(const uint2*)ap;
    const uint2 p1 = *(const uint2*)(ap + 4);
    const uint2 p2 = *(const uint2*)(ap + 8);
    float a[12] = {blo(p0.x), bhi(p0.x), blo(p0.y), bhi(p0.y),
                   blo(p1.x), bhi(p1.x), blo(p1.y), bhi(p1.y),
                   blo(p2.x), bhi(p2.x), blo(p2.y), bhi(p2.y)};
    float mx = a[0];
#pragma unroll
    for (int i = 1; i < 12; i++) mx = fmaxf(mx, a[i]);
    float e[12], sm = 0.f;
#pragma unroll
    for (int i = 0; i < 12; i++) { e[i] = __expf(a[i] - mx); sm += e[i]; }
    const float r = 1.f / sm;
#pragma unroll
    for (int i = 0; i < 12; i++) law[wv][lane * 12 + i] = e[i] * r;
  }

  float rx, ry;
  {
    if (s < 1024) { const int li = s; rx = ((li & 31) + 0.5f) * (1.f / 32); ry = ((li >> 5) + 0.5f) * (1.f / 32); }
    else if (s < 5120) { const int li = s - 1024; rx = ((li & 63) + 0.5f) * (1.f / 64); ry = ((li >> 6) + 0.5f) * (1.f / 64); }
    else { const int li = s - 5120; rx = ((li & 127) + 0.5f) * (1.f / 128); ry = ((li >> 7) + 0.5f) * (1.f / 128); }
  }

  for (int ti = lane; ti < 96; ti += 64) {
    const int h = ti / 12;
    const int rem = ti - h * 12;
    const int lvl = rem >> 2;
    const int wl = 32 << lvl;
    const float fwl = (float)wl;
    const int start = (lvl == 0) ? 0 : ((lvl == 1) ? 1024 : 5120);
    const unsigned op = *(const unsigned*)(oa + (size_t)bs * 288 + 2 * ti);
    const float ox = blo(op), oy = bhi(op);
    const float x = (rx + ox / fwl) * fwl - 0.5f;   // matches ref FP order
    const float y = (ry + oy / fwl) * fwl - 0.5f;
    const float xf = floorf(x), yf = floorf(y);
    const int x0 = (int)xf, y0 = (int)yf;
    const float fx = x - xf, fy = y - yf;
    const bool xv0 = (x0 >= 0) & (x0 < wl), xv1 = (x0 + 1 >= 0) & (x0 + 1 < wl);
    const bool yv0 = (y0 >= 0) & (y0 < wl), yv1 = (y0 + 1 >= 0) & (y0 + 1 < wl);
    const int x0c = min(max(x0, 0), wl - 1), x1c = min(max(x0 + 1, 0), wl - 1);
    const int y0c = min(max(y0, 0), wl - 1), y1c = min(max(y0 + 1, 0), wl - 1);
    const float w = law[wv][ti];
    float4 w4;
    w4.x = (xv0 & yv0) ? w * (1.f - fx) * (1.f - fy) : 0.f;
    w4.y = (xv1 & yv0) ? w * fx * (1.f - fy) : 0.f;
    w4.z = (xv0 & yv1) ? w * (1.f - fx) * fy : 0.f;
    w4.w = (xv1 & yv1) ? w * fx * fy : 0.f;
    const unsigned base = (unsigned)(((b * S_TOT + start) << 8) + h * 32) * 2u;
    uint4 iv;
    iv.x = base + (unsigned)(y0c * wl + x0c) * 512u;
    iv.y = base + (unsigned)(y0c * wl + x1c) * 512u;
    iv.z = base + (unsigned)(y1c * wl + x0c) * 512u;
    iv.w = base + (unsigned)(y1c * wl + x1c) * 512u;
    didx[wv][ti] = iv;
    dwt[wv][ti] = w4;
  }

  const int h = lane >> 3, c = (lane & 7) * 4;
  const char* vb = (const char*)value + c * 2;
  const uint4* ip = &didx[wv][h * 12];
  const float4* wp = &dwt[wv][h * 12];
  float a0 = 0.f, a1 = 0.f, a2 = 0.f, a3 = 0.f;
#pragma unroll
  for (int t = 0; t < 12; t++) {
    const uint4 iv = ip[t];
    const float4 w4 = wp[t];
    const uint2 q00 = *(const uint2*)(vb + iv.x);
    const uint2 q01 = *(const uint2*)(vb + iv.y);
    const uint2 q10 = *(const uint2*)(vb + iv.z);
    const uint2 q11 = *(const uint2*)(vb + iv.w);
    a0 += w4.x * h2lo(q00.x); a1 += w4.x * h2hi(q00.x);
    a2 += w4.x * h2lo(q00.y); a3 += w4.x * h2hi(q00.y);
    a0 += w4.y * h2lo(q01.x); a1 += w4.y * h2hi(q01.x);
    a2 += w4.y * h2lo(q01.y); a3 += w4.y * h2hi(q01.y);
    a0 += w4.z * h2lo(q10.x); a1 += w4.z * h2hi(q10.x);
    a2 += w4.z * h2lo(q10.y); a3 += w4.z * h2hi(q10.y);
    a0 += w4.w * h2lo(q11.x); a1 += w4.w * h2hi(q11.x);
    a2 += w4.w * h2lo(q11.y); a3 += w4.w * h2hi(q11.y);
  }
  uint2 o;
  o.x = (unsigned)f2b(a0) | ((unsigned)f2b(a1) << 16);
  o.y = (unsigned)f2b(a2) | ((unsigned)f2b(a3) << 16);
  *(uint2*)(attn + (size_t)bs * 256 + h * 32 + c) = o;
}

// ---------------- residual + layernorm; bf16 residual stream (in-place) ----------------
__global__ __launch_bounds__(256) void resln_kernel(const unsigned short* __restrict__ x,
                                                    const unsigned short* __restrict__ r,
                                                    const float* __restrict__ g,
                                                    const float* __restrict__ bta,
                                                    unsigned short* __restrict__ ob,
                                                    const unsigned short* __restrict__ pos,
                                                    unsigned short* __restrict__ qb,
                                                    float* __restrict__ fout) {
  const int t = blockIdx.x * 4 + (threadIdx.x >> 6);
  const int lane = threadIdx.x & 63;
  const size_t base = (size_t)t * 256;
  const ushort4 xv = ((const ushort4*)(x + base))[lane];
  const ushort4 rv = ((const ushort4*)(r + base))[lane];
  const float v0 = b2f(xv.x) + b2f(rv.x), v1 = b2f(xv.y) + b2f(rv.y);
  const float v2 = b2f(xv.z) + b2f(rv.z), v3 = b2f(xv.w) + b2f(rv.w);
  float sm = v0 + v1 + v2 + v3;
#pragma unroll
  for (int o = 32; o > 0; o >>= 1) sm += __shfl_xor(sm, o);
  const float mean = sm * (1.f / 256.f);
  const float d0 = v0 - mean, d1 = v1 - mean, d2 = v2 - mean, d3 = v3 - mean;
  float vs = d0 * d0 + d1 * d1 + d2 * d2 + d3 * d3;
#pragma unroll
  for (int o = 32; o > 0; o >>= 1) vs += __shfl_xor(vs, o);
  const float inv = rsqrtf(vs * (1.f / 256.f) + 1e-5f);
  const int c = lane * 4;
  const float o0 = d0 * inv * g[c] + bta[c];
  const float o1 = d1 * inv * g[c + 1] + bta[c + 1];
  const float o2 = d2 * inv * g[c + 2] + bta[c + 2];
  const float o3 = d3 * inv * g[c + 3] + bta[c + 3];
  if (fout) {
    ((float4*)(fout + base))[lane] = make_float4(o0, o1, o2, o3);
  } else {
    ushort4 u;
    u.x = f2b(o0); u.y = f2b(o1); u.z = f2b(o2); u.w = f2b(o3);
    ((ushort4*)(ob + base))[lane] = u;
  }
  if (qb) {
    const ushort4 pv = ((const ushort4*)(pos + base))[lane];
    ushort4 u;
    u.x = f2b(o0 + b2f(pv.x)); u.y = f2b(o1 + b2f(pv.y));
    u.z = f2b(o2 + b2f(pv.z)); u.w = f2b(o3 + b2f(pv.w));
    ((ushort4*)(qb + base))[lane] = u;
  }
}

// ---------------- host ----------------
extern "C" void kernel_launch(void* const* d_in, const int* in_sizes, int n_in,
                              void* d_out, int out_size, void* d_ws, size_t ws_size,
                              hipStream_t stream) {
  (void)in_sizes; (void)n_in; (void)out_size;
  const float* src0 = (const float*)d_in[0];
  const float* pos0 = (const float*)d_in[1];
  const float* src1 = (const float*)d_in[2];
  const float* pos1 = (const float*)d_in[3];
  const float* src2 = (const float*)d_in[4];
  const float* pos2 = (const float*)d_in[5];
  const float* lemb = (const float*)d_in[6];
  const float* Wv = (const float*)d_in[7];   const float* bv = (const float*)d_in[8];
  const float* Wo = (const float*)d_in[9];   const float* bo = (const float*)d_in[10];
  const float* Wa = (const float*)d_in[11];  const float* ba = (const float*)d_in[12];
  const float* Wout = (const float*)d_in[13]; const float* bout = (const float*)d_in[14];
  const float* ln1g = (const float*)d_in[15]; const float* ln1b = (const float*)d_in[16];
  const float* W1 = (const float*)d_in[17];  const float* b1 = (const float*)d_in[18];
  const float* W2 = (const float*)d_in[19];  const float* b2 = (const float*)d_in[20];
  const float* ln2g = (const float*)d_in[21]; const float* ln2b = (const float*)d_in[22];

  const size_t M = M_TOK;
  const size_t SZ16 = 44040192ull;           // M*256*2
  const size_t POOL = 176160768ull;          // M*1024*2
  const size_t NEED = SZ16 + POOL + SZ16 + SZ16 + 8749056ull;   // 316.8 MB
  if (ws_size < NEED) return;

  char* ws = (char*)d_ws;
  unsigned short* slot0b = (unsigned short*)ws;   // 44 MB: value -> wout -> ff (serial reuse)
  unsigned short* valb = slot0b;
  unsigned short* woutb = slot0b;
  unsigned short* ffb = slot0b;
  char* pool = ws + SZ16;
  unsigned short* q_b16 = (unsigned short*)pool;
  unsigned short* oa_b16 = (unsigned short*)pool + M * 256;   // [M,288]: offs|aw
  unsigned short* attn_b16 = (unsigned short*)pool + M * 544;
  unsigned short* h_b16 = (unsigned short*)pool;  // clobbers q/oa/attn (dead by then)
  unsigned short* out_b16 = (unsigned short*)(pool + POOL);
  unsigned short* pos_b16 = out_b16 + M * 256;
  unsigned short* wt = pos_b16 + M * 256;

  unsigned short* wtv = wt;                 // [6][256][256]
  unsigned short* wtoa = wt + 393216;       // [6][288][256] (Wo rows 0..191, Wa 192..287)
  unsigned short* wtw = wt + 835584;        // [6][256][256]
  unsigned short* wt1 = wt + 1228800;       // [6][1024][256]
  unsigned short* wt2 = wt + 2801664;       // [6][256][1024]

  const dim3 b32(32, 8);
  wtrans_kernel<<<dim3(8, 8, 6), b32, 0, stream>>>(Wv, wtv, 256, 256, 65536, 65536);
  wtrans_kernel<<<dim3(6, 8, 6), b32, 0, stream>>>(Wo, wtoa, 256, 192, 49152, 73728);
  wtrans_kernel<<<dim3(3, 8, 6), b32, 0, stream>>>(Wa, wtoa + 192 * 256, 256, 96, 24576, 73728);
  wtrans_kernel<<<dim3(8, 8, 6), b32, 0, stream>>>(Wout, wtw, 256, 256, 65536, 65536);
  wtrans_kernel<<<dim3(32, 8, 6), b32, 0, stream>>>(W1, wt1, 256, 1024, 262144, 262144);
  wtrans_kernel<<<dim3(8, 32, 6), b32, 0, stream>>>(W2, wt2, 1024, 256, 262144, 262144);

  flatten_kernel<<<dim3(32, 8, 4), b32, 0, stream>>>(src0, pos0, lemb, out_b16, pos_b16, q_b16, 1024, 0);
  flatten_kernel<<<dim3(128, 8, 4), b32, 0, stream>>>(src1, pos1, lemb + 256, out_b16, pos_b16, q_b16, 4096, 1024);
  flatten_kernel<<<dim3(512, 8, 4), b32, 0, stream>>>(src2, pos2, lemb + 512, out_b16, pos_b16, q_b16, 16384, 5120);

  for (int l = 0; l < 6; l++) {
    gemm_kernel<0, 1><<<1344, 512, 0, stream>>>(out_b16, wtv + l * 65536, bv + l * 256, bv + l * 256, 256, valb, 256, 256, 2);
    gemm_kernel<0, 0><<<2016, 512, 0, stream>>>(q_b16, wtoa + l * 73728, bo + l * 192, ba + l * 96, 192, oa_b16, 288, 256, 3);
    deform_kernel<<<21504, 256, 0, stream>>>(valb, oa_b16, attn_b16);
    gemm_kernel<0, 0><<<1344, 512, 0, stream>>>(attn_b16, wtw + l * 65536, bout + l * 256, bout + l * 256, 256, woutb, 256, 256, 2);
    resln_kernel<<<21504, 256, 0, stream>>>(out_b16, woutb, ln1g + l * 256, ln1b + l * 256, out_b16, nullptr, nullptr, nullptr);
    gemm_kernel<1, 0><<<5376, 512, 0, stream>>>(out_b16, wt1 + l * 262144, b1 + l * 1024, b1 + l * 1024, 1024, h_b16, 1024, 256, 8);
    gemm_kernel<0, 0><<<1344, 512, 0, stream>>>(h_b16, wt2 + l * 262144, b2 + l * 256, b2 + l * 256, 256, ffb, 256, 1024, 2);
    if (l < 5) {
      resln_kernel<<<21504, 256, 0, stream>>>(out_b16, ffb, ln2g + l * 256, ln2b + l * 256, out_b16, pos_b16, q_b16, nullptr);
    } else {
      resln_kernel<<<21504, 256, 0, stream>>>(out_b16, ffb, ln2g + l * 256, ln2b + l * 256, nullptr, nullptr, nullptr, (float*)d_out);
    }
  }
}

// Round 22
// 2486.313 us; speedup vs baseline: 1.0671x; 1.0671x over previous
//
#include <hip/hip_runtime.h>
#include <hip/hip_fp16.h>
#include <stdint.h>

// ---------------- static problem config ----------------
#define S_TOT 21504
#define M_TOK 86016
// levels: (32,32) start 0, (64,64) start 1024, (128,128) start 5120

typedef __attribute__((ext_vector_type(8))) short bf16x8;
typedef __attribute__((ext_vector_type(4))) float f32x4;

__device__ __forceinline__ unsigned short f2b(float f) {
  union { float f; unsigned u; } v; v.f = f;
  unsigned r = v.u + 0x7FFFu + ((v.u >> 16) & 1u);
  return (unsigned short)(r >> 16);
}
__device__ __forceinline__ unsigned short f2h(float f) {
  __half h = __float2half(f);
  return __half_as_ushort(h);
}
__device__ __forceinline__ float b2f(unsigned short h) {
  union { unsigned u; float f; } v; v.u = ((unsigned)h) << 16;
  return v.f;
}
__device__ __forceinline__ float blo(unsigned u) {
  union { unsigned u; float f; } v; v.u = u << 16; return v.f;
}
__device__ __forceinline__ float bhi(unsigned u) {
  union { unsigned u; float f; } v; v.u = u & 0xffff0000u; return v.f;
}
// fp16 pair access; (float)h folds into v_fma_mix_f32 at the consuming fma
__device__ __forceinline__ float h2lo(unsigned u) {
  union { unsigned u; __half2 h; } v; v.u = u; return __half2float(v.h.x);
}
__device__ __forceinline__ float h2hi(unsigned u) {
  union { unsigned u; __half2 h; } v; v.u = u; return __half2float(v.h.y);
}

// ---------------- bf16 MFMA GEMM (round-20 form, best measured) ----------------
// BM=BN=128, 4 waves, XCD-swizzled 1D grid, double-buffered LDS (1 barrier/32-K),
// coalesced C via LDS bounce. OUTH=1 -> fp16 C (value), else bf16.
#define LSTR 40
#define TSZ (128 * LSTR)
template <int RELU, int OUTH>
__global__ __launch_bounds__(256) void gemm_kernel(
    const unsigned short* __restrict__ A, const unsigned short* __restrict__ Bt,
    const float* __restrict__ bias, const float* __restrict__ bias2, int nsplit,
    unsigned short* __restrict__ C, int N, int K, int ntx) {
  __shared__ unsigned short smem[4 * TSZ];  // [A0 | A1 | B0 | B1], 40 KB
  const int tid = threadIdx.x;
  const int wave = tid >> 6, lane = tid & 63;
  const int nblk = gridDim.x, chunk = nblk >> 3;
  const int bid = blockIdx.x;
  const int swz = (bid & 7) * chunk + (bid >> 3);
  const long m0 = (long)(swz / ntx) * 128;
  const int n0 = (swz % ntx) * 128;
  const int wm = (wave >> 1) * 64, wn = (wave & 1) * 64;

  f32x4 acc[4][4];
#pragma unroll
  for (int i = 0; i < 4; i++)
#pragma unroll
    for (int j = 0; j < 4; j++) acc[i][j] = (f32x4){0.f, 0.f, 0.f, 0.f};

  const int ar = tid >> 2, ak = (tid & 3) * 8;
  int brA = n0 + ar;      if (brA >= N) brA = N - 1;  // clamp OOB weight rows
  int brB = n0 + ar + 64; if (brB >= N) brB = N - 1;
  const unsigned short* a0p = A + (m0 + ar) * (long)K + ak;
  const unsigned short* a1p = A + (m0 + ar + 64) * (long)K + ak;
  const unsigned short* b0p = Bt + (long)brA * K + ak;
  const unsigned short* b1p = Bt + (long)brB * K + ak;
  const int wo0 = ar * LSTR + ak, wo1 = (ar + 64) * LSTR + ak;

  uint4 ra0 = *(const uint4*)a0p;
  uint4 ra1 = *(const uint4*)a1p;
  uint4 rb0 = *(const uint4*)b0p;
  uint4 rb1 = *(const uint4*)b1p;
  *(uint4*)(smem + wo0) = ra0;
  *(uint4*)(smem + wo1) = ra1;
  *(uint4*)(smem + 2 * TSZ + wo0) = rb0;
  *(uint4*)(smem + 2 * TSZ + wo1) = rb1;
  if (32 < K) {
    ra0 = *(const uint4*)(a0p + 32);
    ra1 = *(const uint4*)(a1p + 32);
    rb0 = *(const uint4*)(b0p + 32);
    rb1 = *(const uint4*)(b1p + 32);
  }
  __syncthreads();

#define GEMM_COMPUTE(P)                                                               \
  {                                                                                   \
    const int kk = (lane >> 4) * 8;                                                   \
    const unsigned short* Ab = smem + (P)*TSZ;                                        \
    const unsigned short* Bb = smem + (2 + (P)) * TSZ;                                \
    bf16x8 af[4], bq[4];                                                              \
    _Pragma("unroll") for (int i = 0; i < 4; i++)                                     \
        af[i] = *(const bf16x8*)&Ab[(wm + i * 16 + (lane & 15)) * LSTR + kk];         \
    _Pragma("unroll") for (int j = 0; j < 4; j++)                                     \
        bq[j] = *(const bf16x8*)&Bb[(wn + j * 16 + (lane & 15)) * LSTR + kk];         \
    _Pragma("unroll") for (int i = 0; i < 4; i++)                                     \
        _Pragma("unroll") for (int j = 0; j < 4; j++)                                 \
            acc[i][j] = __builtin_amdgcn_mfma_f32_16x16x32_bf16(af[i], bq[j],         \
                                                                acc[i][j], 0, 0, 0); \
  }

  for (int k0 = 0; k0 < K; k0 += 64) {
    if (k0 + 32 < K) {
      *(uint4*)(smem + TSZ + wo0) = ra0;
      *(uint4*)(smem + TSZ + wo1) = ra1;
      *(uint4*)(smem + 3 * TSZ + wo0) = rb0;
      *(uint4*)(smem + 3 * TSZ + wo1) = rb1;
      if (k0 + 64 < K) {
        ra0 = *(const uint4*)(a0p + k0 + 64);
        ra1 = *(const uint4*)(a1p + k0 + 64);
        rb0 = *(const uint4*)(b0p + k0 + 64);
        rb1 = *(const uint4*)(b1p + k0 + 64);
      }
    }
    GEMM_COMPUTE(0);
    __syncthreads();
    if (k0 + 64 < K) {
      *(uint4*)(smem + wo0) = ra0;
      *(uint4*)(smem + wo1) = ra1;
      *(uint4*)(smem + 2 * TSZ + wo0) = rb0;
      *(uint4*)(smem + 2 * TSZ + wo1) = rb1;
      if (k0 + 96 < K) {
        ra0 = *(const uint4*)(a0p + k0 + 96);
        ra1 = *(const uint4*)(a1p + k0 + 96);
        rb0 = *(const uint4*)(b0p + k0 + 96);
        rb1 = *(const uint4*)(b1p + k0 + 96);
      }
    }
    GEMM_COMPUTE(1);
    __syncthreads();
  }
#undef GEMM_COMPUTE

  // coalesced C-write via LDS bounce (64 rows x 136 stride)
  unsigned short* stage = smem;
  const int colb = lane & 15, rowb = (lane >> 4) * 4;
#pragma unroll
  for (int half = 0; half < 2; half++) {
    __syncthreads();
    if (wm == half * 64) {
#pragma unroll
      for (int j = 0; j < 4; j++) {
        const int n = n0 + wn + j * 16 + colb;
        const float bn = (n < N) ? ((n < nsplit) ? bias[n] : bias2[n - nsplit]) : 0.f;
#pragma unroll
        for (int i = 0; i < 4; i++) {
#pragma unroll
          for (int r = 0; r < 4; r++) {
            float v = acc[i][j][r] + bn;
            if (RELU) v = fmaxf(v, 0.f);
            stage[(i * 16 + rowb + r) * 136 + wn + j * 16 + colb] = OUTH ? f2h(v) : f2b(v);
          }
        }
      }
    }
    __syncthreads();
#pragma unroll
    for (int t = 0; t < 4; t++) {
      const int idx = t * 256 + tid;
      const int rr = idx >> 4;
      const int cc = (idx & 15) * 8;
      const int n = n0 + cc;
      if (n < N) {
        const long m = m0 + half * 64 + rr;
        *(uint4*)(C + m * N + n) = *(const uint4*)(stage + rr * 136 + cc);
      }
    }
  }
}

// ---------------- weight transpose + bf16 convert: [L][K][N] -> [L][N][K] ----------------
__global__ void wtrans_kernel(const float* __restrict__ src, unsigned short* __restrict__ dst,
                              int K, int N, size_t src_lstride, size_t dst_lstride) {
  __shared__ float t[32][33];
  const int tx = threadIdx.x, ty = threadIdx.y;
  const int n0 = blockIdx.x * 32, k0 = blockIdx.y * 32, l = blockIdx.z;
  src += (size_t)l * src_lstride;
  dst += (size_t)l * dst_lstride;
#pragma unroll
  for (int i = 0; i < 4; i++) t[ty * 4 + i][tx] = src[(size_t)(k0 + ty * 4 + i) * N + n0 + tx];
  __syncthreads();
#pragma unroll
  for (int i = 0; i < 4; i++)
    dst[(size_t)(n0 + ty * 4 + i) * K + k0 + tx] = f2b(t[tx][ty * 4 + i]);
}

// ---------------- flatten [B,C,H,W] -> [B,HW,C]; writes residual b16, pos b16, q b16 ----
__global__ void flatten_kernel(const float* __restrict__ src, const float* __restrict__ pos,
                               const float* __restrict__ lemb,
                               unsigned short* __restrict__ outb, unsigned short* __restrict__ posb,
                               unsigned short* __restrict__ qb, int HW, int s0) {
  __shared__ float ts[32][33];
  __shared__ float tp[32][33];
  const int tx = threadIdx.x, ty = threadIdx.y;
  const int hw0 = blockIdx.x * 32, c0 = blockIdx.y * 32, b = blockIdx.z;
  const size_t ibase = ((size_t)b * 256 + c0) * HW + hw0;
#pragma unroll
  for (int i = 0; i < 4; i++) {
    ts[ty * 4 + i][tx] = src[ibase + (size_t)(ty * 4 + i) * HW + tx];
    tp[ty * 4 + i][tx] = pos[ibase + (size_t)(ty * 4 + i) * HW + tx];
  }
  __syncthreads();
#pragma unroll
  for (int i = 0; i < 4; i++) {
    const int sI = s0 + hw0 + ty * 4 + i, c = c0 + tx;
    const size_t o = ((size_t)b * S_TOT + sI) * 256 + c;
    const float sv = ts[tx][ty * 4 + i];
    const unsigned short pb = f2b(tp[tx][ty * 4 + i] + lemb[c]);
    outb[o] = f2b(sv);
    posb[o] = pb;
    qb[o] = f2b(sv + b2f(pb));
  }
}

// ---------------- deformable attention sampling v5: 2 tokens per wave ----------------
// Wave = 2 tokens (tk = lane>>5), 32 lanes/token: head = sl>>2, 8 channels via uint4.
// Halves per-token wave count -> softmax/descriptor/load instruction totals halve;
// per-channel accumulation order unchanged (bit-identical numerics). No barriers
// (law/didx/dwt slices are wave-private).
__global__ __launch_bounds__(256) void deform_kernel(const unsigned short* __restrict__ value,
                                                     const unsigned short* __restrict__ oa,
                                                     unsigned short* __restrict__ attn) {
  __shared__ float law[4][192];
  __shared__ uint4 didx[4][192];
  __shared__ float4 dwt[4][192];
  const int tid = threadIdx.x;
  const int wv = tid >> 6, lane = tid & 63;
  const int tk = lane >> 5, sl = lane & 31;
  const int bs = blockIdx.x * 8 + wv * 2 + tk;
  const int b = bs / S_TOT, s = bs - b * S_TOT;

  if (sl < 8) {  // per-head softmax over NL*NP=12 (head = sl, token = tk)
    const unsigned short* ap = oa + (size_t)bs * 288 + 192 + sl * 12;
    const uint2 p0 = *(const uint2*)ap;
    const uint2 p1 = *(const uint2*)(ap + 4);
    const uint2 p2 = *(const uint2*)(ap + 8);
    float a[12] = {blo(p0.x), bhi(p0.x), blo(p0.y), bhi(p0.y),
                   blo(p1.x), bhi(p1.x), blo(p1.y), bhi(p1.y),
                   blo(p2.x), bhi(p2.x), blo(p2.y), bhi(p2.y)};
    float mx = a[0];
#pragma unroll
    for (int i = 1; i < 12; i++) mx = fmaxf(mx, a[i]);
    float e[12], sm = 0.f;
#pragma unroll
    for (int i = 0; i < 12; i++) { e[i] = __expf(a[i] - mx); sm += e[i]; }
    const float r = 1.f / sm;
#pragma unroll
    for (int i = 0; i < 12; i++) law[wv][tk * 96 + sl * 12 + i] = e[i] * r;
  }

  float rx, ry;
  {
    if (s < 1024) { const int li = s; rx = ((li & 31) + 0.5f) * (1.f / 32); ry = ((li >> 5) + 0.5f) * (1.f / 32); }
    else if (s < 5120) { const int li = s - 1024; rx = ((li & 63) + 0.5f) * (1.f / 64); ry = ((li >> 6) + 0.5f) * (1.f / 64); }
    else { const int li = s - 5120; rx = ((li & 127) + 0.5f) * (1.f / 128); ry = ((li >> 7) + 0.5f) * (1.f / 128); }
  }

  // descriptor stage: 96 taps per token, 32 lanes/token -> 3 uniform iterations
  for (int ti = sl; ti < 96; ti += 32) {
    const int h = ti / 12;
    const int rem = ti - h * 12;
    const int lvl = rem >> 2;
    const int wl = 32 << lvl;
    const float fwl = (float)wl;
    const int start = (lvl == 0) ? 0 : ((lvl == 1) ? 1024 : 5120);
    const unsigned op = *(const unsigned*)(oa + (size_t)bs * 288 + 2 * ti);
    const float ox = blo(op), oy = bhi(op);
    const float x = (rx + ox / fwl) * fwl - 0.5f;   // matches ref FP order
    const float y = (ry + oy / fwl) * fwl - 0.5f;
    const float xf = floorf(x), yf = floorf(y);
    const int x0 = (int)xf, y0 = (int)yf;
    const float fx = x - xf, fy = y - yf;
    const bool xv0 = (x0 >= 0) & (x0 < wl), xv1 = (x0 + 1 >= 0) & (x0 + 1 < wl);
    const bool yv0 = (y0 >= 0) & (y0 < wl), yv1 = (y0 + 1 >= 0) & (y0 + 1 < wl);
    const int x0c = min(max(x0, 0), wl - 1), x1c = min(max(x0 + 1, 0), wl - 1);
    const int y0c = min(max(y0, 0), wl - 1), y1c = min(max(y0 + 1, 0), wl - 1);
    const float w = law[wv][tk * 96 + ti];
    float4 w4;
    w4.x = (xv0 & yv0) ? w * (1.f - fx) * (1.f - fy) : 0.f;
    w4.y = (xv1 & yv0) ? w * fx * (1.f - fy) : 0.f;
    w4.z = (xv0 & yv1) ? w * (1.f - fx) * fy : 0.f;
    w4.w = (xv1 & yv1) ? w * fx * fy : 0.f;
    // BYTE offsets (x2): gather loop does zero scaling arithmetic.
    const unsigned base = (unsigned)(((b * S_TOT + start) << 8) + h * 32) * 2u;
    uint4 iv;
    iv.x = base + (unsigned)(y0c * wl + x0c) * 512u;
    iv.y = base + (unsigned)(y0c * wl + x1c) * 512u;
    iv.z = base + (unsigned)(y1c * wl + x0c) * 512u;
    iv.w = base + (unsigned)(y1c * wl + x1c) * 512u;
    didx[wv][tk * 96 + ti] = iv;
    dwt[wv][tk * 96 + ti] = w4;
  }

  // gather: head = sl>>2, 8 channels = (sl&3)*8 via uint4 (16B) loads
  const int h = sl >> 2, cg = sl & 3;
  const char* vb = (const char*)value + cg * 16;  // per-lane channel base (bytes)
  const uint4* ip = &didx[wv][tk * 96 + h * 12];
  const float4* wp = &dwt[wv][tk * 96 + h * 12];
  float a0 = 0.f, a1 = 0.f, a2 = 0.f, a3 = 0.f;
  float a4 = 0.f, a5 = 0.f, a6 = 0.f, a7 = 0.f;
#pragma unroll
  for (int t = 0; t < 12; t++) {
    const uint4 iv = ip[t];
    const float4 w4 = wp[t];
    const uint4 q00 = *(const uint4*)(vb + iv.x);
    const uint4 q01 = *(const uint4*)(vb + iv.y);
    const uint4 q10 = *(const uint4*)(vb + iv.z);
    const uint4 q11 = *(const uint4*)(vb + iv.w);
    a0 += w4.x * h2lo(q00.x); a1 += w4.x * h2hi(q00.x);
    a2 += w4.x * h2lo(q00.y); a3 += w4.x * h2hi(q00.y);
    a4 += w4.x * h2lo(q00.z); a5 += w4.x * h2hi(q00.z);
    a6 += w4.x * h2lo(q00.w); a7 += w4.x * h2hi(q00.w);
    a0 += w4.y * h2lo(q01.x); a1 += w4.y * h2hi(q01.x);
    a2 += w4.y * h2lo(q01.y); a3 += w4.y * h2hi(q01.y);
    a4 += w4.y * h2lo(q01.z); a5 += w4.y * h2hi(q01.z);
    a6 += w4.y * h2lo(q01.w); a7 += w4.y * h2hi(q01.w);
    a0 += w4.z * h2lo(q10.x); a1 += w4.z * h2hi(q10.x);
    a2 += w4.z * h2lo(q10.y); a3 += w4.z * h2hi(q10.y);
    a4 += w4.z * h2lo(q10.z); a5 += w4.z * h2hi(q10.z);
    a6 += w4.z * h2lo(q10.w); a7 += w4.z * h2hi(q10.w);
    a0 += w4.w * h2lo(q11.x); a1 += w4.w * h2hi(q11.x);
    a2 += w4.w * h2lo(q11.y); a3 += w4.w * h2hi(q11.y);
    a4 += w4.w * h2lo(q11.z); a5 += w4.w * h2hi(q11.z);
    a6 += w4.w * h2lo(q11.w); a7 += w4.w * h2hi(q11.w);
  }
  uint4 o;
  o.x = (unsigned)f2b(a0) | ((unsigned)f2b(a1) << 16);
  o.y = (unsigned)f2b(a2) | ((unsigned)f2b(a3) << 16);
  o.z = (unsigned)f2b(a4) | ((unsigned)f2b(a5) << 16);
  o.w = (unsigned)f2b(a6) | ((unsigned)f2b(a7) << 16);
  *(uint4*)(attn + (size_t)bs * 256 + h * 32 + cg * 8) = o;
}

// ---------------- residual + layernorm; bf16 residual stream (in-place) ----------------
__global__ __launch_bounds__(256) void resln_kernel(const unsigned short* __restrict__ x,
                                                    const unsigned short* __restrict__ r,
                                                    const float* __restrict__ g,
                                                    const float* __restrict__ bta,
                                                    unsigned short* __restrict__ ob,
                                                    const unsigned short* __restrict__ pos,
                                                    unsigned short* __restrict__ qb,
                                                    float* __restrict__ fout) {
  const int t = blockIdx.x * 4 + (threadIdx.x >> 6);
  const int lane = threadIdx.x & 63;
  const size_t base = (size_t)t * 256;
  const ushort4 xv = ((const ushort4*)(x + base))[lane];
  const ushort4 rv = ((const ushort4*)(r + base))[lane];
  const float v0 = b2f(xv.x) + b2f(rv.x), v1 = b2f(xv.y) + b2f(rv.y);
  const float v2 = b2f(xv.z) + b2f(rv.z), v3 = b2f(xv.w) + b2f(rv.w);
  float sm = v0 + v1 + v2 + v3;
#pragma unroll
  for (int o = 32; o > 0; o >>= 1) sm += __shfl_xor(sm, o);
  const float mean = sm * (1.f / 256.f);
  const float d0 = v0 - mean, d1 = v1 - mean, d2 = v2 - mean, d3 = v3 - mean;
  float vs = d0 * d0 + d1 * d1 + d2 * d2 + d3 * d3;
#pragma unroll
  for (int o = 32; o > 0; o >>= 1) vs += __shfl_xor(vs, o);
  const float inv = rsqrtf(vs * (1.f / 256.f) + 1e-5f);
  const int c = lane * 4;
  const float o0 = d0 * inv * g[c] + bta[c];
  const float o1 = d1 * inv * g[c + 1] + bta[c + 1];
  const float o2 = d2 * inv * g[c + 2] + bta[c + 2];
  const float o3 = d3 * inv * g[c + 3] + bta[c + 3];
  if (fout) {
    ((float4*)(fout + base))[lane] = make_float4(o0, o1, o2, o3);
  } else {
    ushort4 u;
    u.x = f2b(o0); u.y = f2b(o1); u.z = f2b(o2); u.w = f2b(o3);
    ((ushort4*)(ob + base))[lane] = u;
  }
  if (qb) {
    const ushort4 pv = ((const ushort4*)(pos + base))[lane];
    ushort4 u;
    u.x = f2b(o0 + b2f(pv.x)); u.y = f2b(o1 + b2f(pv.y));
    u.z = f2b(o2 + b2f(pv.z)); u.w = f2b(o3 + b2f(pv.w));
    ((ushort4*)(qb + base))[lane] = u;
  }
}

// ---------------- host ----------------
extern "C" void kernel_launch(void* const* d_in, const int* in_sizes, int n_in,
                              void* d_out, int out_size, void* d_ws, size_t ws_size,
                              hipStream_t stream) {
  (void)in_sizes; (void)n_in; (void)out_size;
  const float* src0 = (const float*)d_in[0];
  const float* pos0 = (const float*)d_in[1];
  const float* src1 = (const float*)d_in[2];
  const float* pos1 = (const float*)d_in[3];
  const float* src2 = (const float*)d_in[4];
  const float* pos2 = (const float*)d_in[5];
  const float* lemb = (const float*)d_in[6];
  const float* Wv = (const float*)d_in[7];   const float* bv = (const float*)d_in[8];
  const float* Wo = (const float*)d_in[9];   const float* bo = (const float*)d_in[10];
  const float* Wa = (const float*)d_in[11];  const float* ba = (const float*)d_in[12];
  const float* Wout = (const float*)d_in[13]; const float* bout = (const float*)d_in[14];
  const float* ln1g = (const float*)d_in[15]; const float* ln1b = (const float*)d_in[16];
  const float* W1 = (const float*)d_in[17];  const float* b1 = (const float*)d_in[18];
  const float* W2 = (const float*)d_in[19];  const float* b2 = (const float*)d_in[20];
  const float* ln2g = (const float*)d_in[21]; const float* ln2b = (const float*)d_in[22];

  const size_t M = M_TOK;
  const size_t SZ16 = 44040192ull;           // M*256*2
  const size_t POOL = 176160768ull;          // M*1024*2
  const size_t NEED = SZ16 + POOL + SZ16 + SZ16 + 8749056ull;   // 316.8 MB
  if (ws_size < NEED) return;

  char* ws = (char*)d_ws;
  unsigned short* slot0b = (unsigned short*)ws;   // 44 MB: value -> wout -> ff (serial reuse)
  unsigned short* valb = slot0b;
  unsigned short* woutb = slot0b;
  unsigned short* ffb = slot0b;
  char* pool = ws + SZ16;
  unsigned short* q_b16 = (unsigned short*)pool;
  unsigned short* oa_b16 = (unsigned short*)pool + M * 256;   // [M,288]: offs|aw
  unsigned short* attn_b16 = (unsigned short*)pool + M * 544;
  unsigned short* h_b16 = (unsigned short*)pool;  // clobbers q/oa/attn (dead by then)
  unsigned short* out_b16 = (unsigned short*)(pool + POOL);
  unsigned short* pos_b16 = out_b16 + M * 256;
  unsigned short* wt = pos_b16 + M * 256;

  unsigned short* wtv = wt;                 // [6][256][256]
  unsigned short* wtoa = wt + 393216;       // [6][288][256] (Wo rows 0..191, Wa 192..287)
  unsigned short* wtw = wt + 835584;        // [6][256][256]
  unsigned short* wt1 = wt + 1228800;       // [6][1024][256]
  unsigned short* wt2 = wt + 2801664;       // [6][256][1024]

  const dim3 b32(32, 8);
  wtrans_kernel<<<dim3(8, 8, 6), b32, 0, stream>>>(Wv, wtv, 256, 256, 65536, 65536);
  wtrans_kernel<<<dim3(6, 8, 6), b32, 0, stream>>>(Wo, wtoa, 256, 192, 49152, 73728);
  wtrans_kernel<<<dim3(3, 8, 6), b32, 0, stream>>>(Wa, wtoa + 192 * 256, 256, 96, 24576, 73728);
  wtrans_kernel<<<dim3(8, 8, 6), b32, 0, stream>>>(Wout, wtw, 256, 256, 65536, 65536);
  wtrans_kernel<<<dim3(32, 8, 6), b32, 0, stream>>>(W1, wt1, 256, 1024, 262144, 262144);
  wtrans_kernel<<<dim3(8, 32, 6), b32, 0, stream>>>(W2, wt2, 1024, 256, 262144, 262144);

  flatten_kernel<<<dim3(32, 8, 4), b32, 0, stream>>>(src0, pos0, lemb, out_b16, pos_b16, q_b16, 1024, 0);
  flatten_kernel<<<dim3(128, 8, 4), b32, 0, stream>>>(src1, pos1, lemb + 256, out_b16, pos_b16, q_b16, 4096, 1024);
  flatten_kernel<<<dim3(512, 8, 4), b32, 0, stream>>>(src2, pos2, lemb + 512, out_b16, pos_b16, q_b16, 16384, 5120);

  for (int l = 0; l < 6; l++) {
    gemm_kernel<0, 1><<<1344, 256, 0, stream>>>(out_b16, wtv + l * 65536, bv + l * 256, bv + l * 256, 256, valb, 256, 256, 2);
    gemm_kernel<0, 0><<<2016, 256, 0, stream>>>(q_b16, wtoa + l * 73728, bo + l * 192, ba + l * 96, 192, oa_b16, 288, 256, 3);
    deform_kernel<<<10752, 256, 0, stream>>>(valb, oa_b16, attn_b16);
    gemm_kernel<0, 0><<<1344, 256, 0, stream>>>(attn_b16, wtw + l * 65536, bout + l * 256, bout + l * 256, 256, woutb, 256, 256, 2);
    resln_kernel<<<21504, 256, 0, stream>>>(out_b16, woutb, ln1g + l * 256, ln1b + l * 256, out_b16, nullptr, nullptr, nullptr);
    gemm_kernel<1, 0><<<5376, 256, 0, stream>>>(out_b16, wt1 + l * 262144, b1 + l * 1024, b1 + l * 1024, 1024, h_b16, 1024, 256, 8);
    gemm_kernel<0, 0><<<1344, 256, 0, stream>>>(h_b16, wt2 + l * 262144, b2 + l * 256, b2 + l * 256, 256, ffb, 256, 1024, 2);
    if (l < 5) {
      resln_kernel<<<21504, 256, 0, stream>>>(out_b16, ffb, ln2g + l * 256, ln2b + l * 256, out_b16, pos_b16, q_b16, nullptr);
    } else {
      resln_kernel<<<21504, 256, 0, stream>>>(out_b16, ffb, ln2g + l * 256, ln2b + l * 256, nullptr, nullptr, nullptr, (float*)d_out);
    }
  }
}

// Round 23
// 2462.145 us; speedup vs baseline: 1.0776x; 1.0098x over previous
//
#include <hip/hip_runtime.h>
#include <hip/hip_fp16.h>
#include <stdint.h>

// ---------------- static problem config ----------------
#define S_TOT 21504
#define M_TOK 86016
// levels: (32,32) start 0, (64,64) start 1024, (128,128) start 5120

typedef __attribute__((ext_vector_type(8))) short bf16x8;
typedef __attribute__((ext_vector_type(4))) float f32x4;

__device__ __forceinline__ unsigned short f2b(float f) {
  union { float f; unsigned u; } v; v.f = f;
  unsigned r = v.u + 0x7FFFu + ((v.u >> 16) & 1u);
  return (unsigned short)(r >> 16);
}
__device__ __forceinline__ unsigned short f2h(float f) {
  __half h = __float2half(f);
  return __half_as_ushort(h);
}
__device__ __forceinline__ float b2f(unsigned short h) {
  union { unsigned u; float f; } v; v.u = ((unsigned)h) << 16;
  return v.f;
}
__device__ __forceinline__ float blo(unsigned u) {
  union { unsigned u; float f; } v; v.u = u << 16; return v.f;
}
__device__ __forceinline__ float bhi(unsigned u) {
  union { unsigned u; float f; } v; v.u = u & 0xffff0000u; return v.f;
}
// fp16 pair access; (float)h folds into v_fma_mix_f32 at the consuming fma
__device__ __forceinline__ float h2lo(unsigned u) {
  union { unsigned u; __half2 h; } v; v.u = u; return __half2float(v.h.x);
}
__device__ __forceinline__ float h2hi(unsigned u) {
  union { unsigned u; __half2 h; } v; v.u = u; return __half2float(v.h.y);
}

// global -> LDS direct DMA, 16B/lane; LDS dest = wave-uniform base + lane*16.
// (round-4 proven cast: direct addrspace casts, no uintptr round-trip)
__device__ __forceinline__ void gload16(const unsigned short* g, unsigned short* l) {
  __builtin_amdgcn_global_load_lds(
      (const __attribute__((address_space(1))) unsigned int*)(const void*)g,
      (__attribute__((address_space(3))) unsigned int*)(void*)l, 16, 0, 0);
}

// ---------------- bf16 MFMA GEMM: C = A * Bt^T + bias ----------------
// BM=BN=128, 4 waves, XCD-swizzled 1D grid, coalesced C via LDS bounce.
// Round-20 double-buffer (1 barrier/32-K) with STAGE = global_load_lds DMA:
// DMA for tile t+1 is issued BEFORE computing tile t, so the barrier's vmcnt
// drain lands after a full MFMA phase of cover. Linear [128][32] LDS layout
// (chunk tid <-> byte off tid*16) as required by the wave-uniform DMA dest.
#define TSZ 4096  // ushorts per 128x32 tile (8 KB)
template <int RELU, int OUTH>
__global__ __launch_bounds__(256) void gemm_kernel(
    const unsigned short* __restrict__ A, const unsigned short* __restrict__ Bt,
    const float* __restrict__ bias, const float* __restrict__ bias2, int nsplit,
    unsigned short* __restrict__ C, int N, int K, int ntx) {
  __shared__ unsigned short smem[4 * TSZ];  // [A0 | A1 | B0 | B1], 32 KB
  const int tid = threadIdx.x;
  const int wave = tid >> 6, lane = tid & 63;
  const int nblk = gridDim.x, chunk = nblk >> 3;
  const int bid = blockIdx.x;
  const int swz = (bid & 7) * chunk + (bid >> 3);
  const long m0 = (long)(swz / ntx) * 128;
  const int n0 = (swz % ntx) * 128;
  const int wm = (wave >> 1) * 64, wn = (wave & 1) * 64;

  f32x4 acc[4][4];
#pragma unroll
  for (int i = 0; i < 4; i++)
#pragma unroll
    for (int j = 0; j < 4; j++) acc[i][j] = (f32x4){0.f, 0.f, 0.f, 0.f};

  // chunk tid = (row tid>>2, k-words (tid&3)*8); linear LDS off = tid*8 ushorts.
  const int ar = tid >> 2, ak = (tid & 3) * 8;
  int brA = n0 + ar;      if (brA >= N) brA = N - 1;  // clamp OOB weight rows
  int brB = n0 + ar + 64; if (brB >= N) brB = N - 1;
  const unsigned short* a0p = A + (m0 + ar) * (long)K + ak;
  const unsigned short* a1p = A + (m0 + ar + 64) * (long)K + ak;
  const unsigned short* b0p = Bt + (long)brA * K + ak;
  const unsigned short* b1p = Bt + (long)brB * K + ak;
  const int wb = wave * 512;  // wave-uniform LDS base (ushorts); HW adds lane*16B

#define GEMM_STAGE(P, KOFF)                                        \
  {                                                                \
    gload16(a0p + (KOFF), smem + (P)*TSZ + wb);                    \
    gload16(a1p + (KOFF), smem + (P)*TSZ + 2048 + wb);             \
    gload16(b0p + (KOFF), smem + (2 + (P)) * TSZ + wb);            \
    gload16(b1p + (KOFF), smem + (2 + (P)) * TSZ + 2048 + wb);     \
  }

#define GEMM_COMPUTE(P)                                                               \
  {                                                                                   \
    const int kk = (lane >> 4) * 8;                                                   \
    const unsigned short* Ab = smem + (P)*TSZ;                                        \
    const unsigned short* Bb = smem + (2 + (P)) * TSZ;                                \
    bf16x8 af[4], bq[4];                                                              \
    _Pragma("unroll") for (int i = 0; i < 4; i++)                                     \
        af[i] = *(const bf16x8*)&Ab[(wm + i * 16 + (lane & 15)) * 32 + kk];           \
    _Pragma("unroll") for (int j = 0; j < 4; j++)                                     \
        bq[j] = *(const bf16x8*)&Bb[(wn + j * 16 + (lane & 15)) * 32 + kk];           \
    _Pragma("unroll") for (int i = 0; i < 4; i++)                                     \
        _Pragma("unroll") for (int j = 0; j < 4; j++)                                 \
            acc[i][j] = __builtin_amdgcn_mfma_f32_16x16x32_bf16(af[i], bq[j],         \
                                                                acc[i][j], 0, 0, 0); \
  }

  GEMM_STAGE(0, 0);     // tile 0 -> buf0 (DMA)
  __syncthreads();      // drains vmcnt: tile 0 resident

  for (int k0 = 0; k0 < K; k0 += 64) {
    if (k0 + 32 < K) GEMM_STAGE(1, k0 + 32);  // DMA next tile; lands under compute
    GEMM_COMPUTE(0);
    __syncthreads();
    if (k0 + 64 < K) GEMM_STAGE(0, k0 + 64);
    GEMM_COMPUTE(1);
    __syncthreads();
  }
#undef GEMM_COMPUTE
#undef GEMM_STAGE

  // coalesced C-write via LDS bounce (64 rows x 136 stride; 8704 <= 16384 avail)
  unsigned short* stage = smem;
  const int colb = lane & 15, rowb = (lane >> 4) * 4;
#pragma unroll
  for (int half = 0; half < 2; half++) {
    __syncthreads();
    if (wm == half * 64) {
#pragma unroll
      for (int j = 0; j < 4; j++) {
        const int n = n0 + wn + j * 16 + colb;
        const float bn = (n < N) ? ((n < nsplit) ? bias[n] : bias2[n - nsplit]) : 0.f;
#pragma unroll
        for (int i = 0; i < 4; i++) {
#pragma unroll
          for (int r = 0; r < 4; r++) {
            float v = acc[i][j][r] + bn;
            if (RELU) v = fmaxf(v, 0.f);
            stage[(i * 16 + rowb + r) * 136 + wn + j * 16 + colb] = OUTH ? f2h(v) : f2b(v);
          }
        }
      }
    }
    __syncthreads();
#pragma unroll
    for (int t = 0; t < 4; t++) {
      const int idx = t * 256 + tid;
      const int rr = idx >> 4;
      const int cc = (idx & 15) * 8;
      const int n = n0 + cc;
      if (n < N) {
        const long m = m0 + half * 64 + rr;
        *(uint4*)(C + m * N + n) = *(const uint4*)(stage + rr * 136 + cc);
      }
    }
  }
}

// ---------------- weight transpose + bf16 convert: [L][K][N] -> [L][N][K] ----------------
__global__ void wtrans_kernel(const float* __restrict__ src, unsigned short* __restrict__ dst,
                              int K, int N, size_t src_lstride, size_t dst_lstride) {
  __shared__ float t[32][33];
  const int tx = threadIdx.x, ty = threadIdx.y;
  const int n0 = blockIdx.x * 32, k0 = blockIdx.y * 32, l = blockIdx.z;
  src += (size_t)l * src_lstride;
  dst += (size_t)l * dst_lstride;
#pragma unroll
  for (int i = 0; i < 4; i++) t[ty * 4 + i][tx] = src[(size_t)(k0 + ty * 4 + i) * N + n0 + tx];
  __syncthreads();
#pragma unroll
  for (int i = 0; i < 4; i++)
    dst[(size_t)(n0 + ty * 4 + i) * K + k0 + tx] = f2b(t[tx][ty * 4 + i]);
}

// ---------------- flatten [B,C,H,W] -> [B,HW,C]; writes residual b16, pos b16, q b16 ----
__global__ void flatten_kernel(const float* __restrict__ src, const float* __restrict__ pos,
                               const float* __restrict__ lemb,
                               unsigned short* __restrict__ outb, unsigned short* __restrict__ posb,
                               unsigned short* __restrict__ qb, int HW, int s0) {
  __shared__ float ts[32][33];
  __shared__ float tp[32][33];
  const int tx = threadIdx.x, ty = threadIdx.y;
  const int hw0 = blockIdx.x * 32, c0 = blockIdx.y * 32, b = blockIdx.z;
  const size_t ibase = ((size_t)b * 256 + c0) * HW + hw0;
#pragma unroll
  for (int i = 0; i < 4; i++) {
    ts[ty * 4 + i][tx] = src[ibase + (size_t)(ty * 4 + i) * HW + tx];
    tp[ty * 4 + i][tx] = pos[ibase + (size_t)(ty * 4 + i) * HW + tx];
  }
  __syncthreads();
#pragma unroll
  for (int i = 0; i < 4; i++) {
    const int sI = s0 + hw0 + ty * 4 + i, c = c0 + tx;
    const size_t o = ((size_t)b * S_TOT + sI) * 256 + c;
    const float sv = ts[tx][ty * 4 + i];
    const unsigned short pb = f2b(tp[tx][ty * 4 + i] + lemb[c]);
    outb[o] = f2b(sv);
    posb[o] = pb;
    qb[o] = f2b(sv + b2f(pb));
  }
}

// ---------------- deformable attention sampling v5: 2 tokens per wave ----------------
// Wave = 2 tokens (tk = lane>>5), 32 lanes/token: head = sl>>2, 8 channels via uint4.
// No barriers (law/didx/dwt slices are wave-private).
__global__ __launch_bounds__(256) void deform_kernel(const unsigned short* __restrict__ value,
                                                     const unsigned short* __restrict__ oa,
                                                     unsigned short* __restrict__ attn) {
  __shared__ float law[4][192];
  __shared__ uint4 didx[4][192];
  __shared__ float4 dwt[4][192];
  const int tid = threadIdx.x;
  const int wv = tid >> 6, lane = tid & 63;
  const int tk = lane >> 5, sl = lane & 31;
  const int bs = blockIdx.x * 8 + wv * 2 + tk;
  const int b = bs / S_TOT, s = bs - b * S_TOT;

  if (sl < 8) {  // per-head softmax over NL*NP=12 (head = sl, token = tk)
    const unsigned short* ap = oa + (size_t)bs * 288 + 192 + sl * 12;
    const uint2 p0 = *(const uint2*)ap;
    const uint2 p1 = *(const uint2*)(ap + 4);
    const uint2 p2 = *(const uint2*)(ap + 8);
    float a[12] = {blo(p0.x), bhi(p0.x), blo(p0.y), bhi(p0.y),
                   blo(p1.x), bhi(p1.x), blo(p1.y), bhi(p1.y),
                   blo(p2.x), bhi(p2.x), blo(p2.y), bhi(p2.y)};
    float mx = a[0];
#pragma unroll
    for (int i = 1; i < 12; i++) mx = fmaxf(mx, a[i]);
    float e[12], sm = 0.f;
#pragma unroll
    for (int i = 0; i < 12; i++) { e[i] = __expf(a[i] - mx); sm += e[i]; }
    const float r = 1.f / sm;
#pragma unroll
    for (int i = 0; i < 12; i++) law[wv][tk * 96 + sl * 12 + i] = e[i] * r;
  }

  float rx, ry;
  {
    if (s < 1024) { const int li = s; rx = ((li & 31) + 0.5f) * (1.f / 32); ry = ((li >> 5) + 0.5f) * (1.f / 32); }
    else if (s < 5120) { const int li = s - 1024; rx = ((li & 63) + 0.5f) * (1.f / 64); ry = ((li >> 6) + 0.5f) * (1.f / 64); }
    else { const int li = s - 5120; rx = ((li & 127) + 0.5f) * (1.f / 128); ry = ((li >> 7) + 0.5f) * (1.f / 128); }
  }

  for (int ti = sl; ti < 96; ti += 32) {
    const int h = ti / 12;
    const int rem = ti - h * 12;
    const int lvl = rem >> 2;
    const int wl = 32 << lvl;
    const float fwl = (float)wl;
    const int start = (lvl == 0) ? 0 : ((lvl == 1) ? 1024 : 5120);
    const unsigned op = *(const unsigned*)(oa + (size_t)bs * 288 + 2 * ti);
    const float ox = blo(op), oy = bhi(op);
    const float x = (rx + ox / fwl) * fwl - 0.5f;   // matches ref FP order
    const float y = (ry + oy / fwl) * fwl - 0.5f;
    const float xf = floorf(x), yf = floorf(y);
    const int x0 = (int)xf, y0 = (int)yf;
    const float fx = x - xf, fy = y - yf;
    const bool xv0 = (x0 >= 0) & (x0 < wl), xv1 = (x0 + 1 >= 0) & (x0 + 1 < wl);
    const bool yv0 = (y0 >= 0) & (y0 < wl), yv1 = (y0 + 1 >= 0) & (y0 + 1 < wl);
    const int x0c = min(max(x0, 0), wl - 1), x1c = min(max(x0 + 1, 0), wl - 1);
    const int y0c = min(max(y0, 0), wl - 1), y1c = min(max(y0 + 1, 0), wl - 1);
    const float w = law[wv][tk * 96 + ti];
    float4 w4;
    w4.x = (xv0 & yv0) ? w * (1.f - fx) * (1.f - fy) : 0.f;
    w4.y = (xv1 & yv0) ? w * fx * (1.f - fy) : 0.f;
    w4.z = (xv0 & yv1) ? w * (1.f - fx) * fy : 0.f;
    w4.w = (xv1 & yv1) ? w * fx * fy : 0.f;
    const unsigned base = (unsigned)(((b * S_TOT + start) << 8) + h * 32) * 2u;
    uint4 iv;
    iv.x = base + (unsigned)(y0c * wl + x0c) * 512u;
    iv.y = base + (unsigned)(y0c * wl + x1c) * 512u;
    iv.z = base + (unsigned)(y1c * wl + x0c) * 512u;
    iv.w = base + (unsigned)(y1c * wl + x1c) * 512u;
    didx[wv][tk * 96 + ti] = iv;
    dwt[wv][tk * 96 + ti] = w4;
  }

  const int h = sl >> 2, cg = sl & 3;
  const char* vb = (const char*)value + cg * 16;
  const uint4* ip = &didx[wv][tk * 96 + h * 12];
  const float4* wp = &dwt[wv][tk * 96 + h * 12];
  float a0 = 0.f, a1 = 0.f, a2 = 0.f, a3 = 0.f;
  float a4 = 0.f, a5 = 0.f, a6 = 0.f, a7 = 0.f;
#pragma unroll
  for (int t = 0; t < 12; t++) {
    const uint4 iv = ip[t];
    const float4 w4 = wp[t];
    const uint4 q00 = *(const uint4*)(vb + iv.x);
    const uint4 q01 = *(const uint4*)(vb + iv.y);
    const uint4 q10 = *(const uint4*)(vb + iv.z);
    const uint4 q11 = *(const uint4*)(vb + iv.w);
    a0 += w4.x * h2lo(q00.x); a1 += w4.x * h2hi(q00.x);
    a2 += w4.x * h2lo(q00.y); a3 += w4.x * h2hi(q00.y);
    a4 += w4.x * h2lo(q00.z); a5 += w4.x * h2hi(q00.z);
    a6 += w4.x * h2lo(q00.w); a7 += w4.x * h2hi(q00.w);
    a0 += w4.y * h2lo(q01.x); a1 += w4.y * h2hi(q01.x);
    a2 += w4.y * h2lo(q01.y); a3 += w4.y * h2hi(q01.y);
    a4 += w4.y * h2lo(q01.z); a5 += w4.y * h2hi(q01.z);
    a6 += w4.y * h2lo(q01.w); a7 += w4.y * h2hi(q01.w);
    a0 += w4.z * h2lo(q10.x); a1 += w4.z * h2hi(q10.x);
    a2 += w4.z * h2lo(q10.y); a3 += w4.z * h2hi(q10.y);
    a4 += w4.z * h2lo(q10.z); a5 += w4.z * h2hi(q10.z);
    a6 += w4.z * h2lo(q10.w); a7 += w4.z * h2hi(q10.w);
    a0 += w4.w * h2lo(q11.x); a1 += w4.w * h2hi(q11.x);
    a2 += w4.w * h2lo(q11.y); a3 += w4.w * h2hi(q11.y);
    a4 += w4.w * h2lo(q11.z); a5 += w4.w * h2hi(q11.z);
    a6 += w4.w * h2lo(q11.w); a7 += w4.w * h2hi(q11.w);
  }
  uint4 o;
  o.x = (unsigned)f2b(a0) | ((unsigned)f2b(a1) << 16);
  o.y = (unsigned)f2b(a2) | ((unsigned)f2b(a3) << 16);
  o.z = (unsigned)f2b(a4) | ((unsigned)f2b(a5) << 16);
  o.w = (unsigned)f2b(a6) | ((unsigned)f2b(a7) << 16);
  *(uint4*)(attn + (size_t)bs * 256 + h * 32 + cg * 8) = o;
}

// ---------------- residual + layernorm; bf16 residual stream (in-place) ----------------
__global__ __launch_bounds__(256) void resln_kernel(const unsigned short* __restrict__ x,
                                                    const unsigned short* __restrict__ r,
                                                    const float* __restrict__ g,
                                                    const float* __restrict__ bta,
                                                    unsigned short* __restrict__ ob,
                                                    const unsigned short* __restrict__ pos,
                                                    unsigned short* __restrict__ qb,
                                                    float* __restrict__ fout) {
  const int t = blockIdx.x * 4 + (threadIdx.x >> 6);
  const int lane = threadIdx.x & 63;
  const size_t base = (size_t)t * 256;
  const ushort4 xv = ((const ushort4*)(x + base))[lane];
  const ushort4 rv = ((const ushort4*)(r + base))[lane];
  const float v0 = b2f(xv.x) + b2f(rv.x), v1 = b2f(xv.y) + b2f(rv.y);
  const float v2 = b2f(xv.z) + b2f(rv.z), v3 = b2f(xv.w) + b2f(rv.w);
  float sm = v0 + v1 + v2 + v3;
#pragma unroll
  for (int o = 32; o > 0; o >>= 1) sm += __shfl_xor(sm, o);
  const float mean = sm * (1.f / 256.f);
  const float d0 = v0 - mean, d1 = v1 - mean, d2 = v2 - mean, d3 = v3 - mean;
  float vs = d0 * d0 + d1 * d1 + d2 * d2 + d3 * d3;
#pragma unroll
  for (int o = 32; o > 0; o >>= 1) vs += __shfl_xor(vs, o);
  const float inv = rsqrtf(vs * (1.f / 256.f) + 1e-5f);
  const int c = lane * 4;
  const float o0 = d0 * inv * g[c] + bta[c];
  const float o1 = d1 * inv * g[c + 1] + bta[c + 1];
  const float o2 = d2 * inv * g[c + 2] + bta[c + 2];
  const float o3 = d3 * inv * g[c + 3] + bta[c + 3];
  if (fout) {
    ((float4*)(fout + base))[lane] = make_float4(o0, o1, o2, o3);
  } else {
    ushort4 u;
    u.x = f2b(o0); u.y = f2b(o1); u.z = f2b(o2); u.w = f2b(o3);
    ((ushort4*)(ob + base))[lane] = u;
  }
  if (qb) {
    const ushort4 pv = ((const ushort4*)(pos + base))[lane];
    ushort4 u;
    u.x = f2b(o0 + b2f(pv.x)); u.y = f2b(o1 + b2f(pv.y));
    u.z = f2b(o2 + b2f(pv.z)); u.w = f2b(o3 + b2f(pv.w));
    ((ushort4*)(qb + base))[lane] = u;
  }
}

// ---------------- host ----------------
extern "C" void kernel_launch(void* const* d_in, const int* in_sizes, int n_in,
                              void* d_out, int out_size, void* d_ws, size_t ws_size,
                              hipStream_t stream) {
  (void)in_sizes; (void)n_in; (void)out_size;
  const float* src0 = (const float*)d_in[0];
  const float* pos0 = (const float*)d_in[1];
  const float* src1 = (const float*)d_in[2];
  const float* pos1 = (const float*)d_in[3];
  const float* src2 = (const float*)d_in[4];
  const float* pos2 = (const float*)d_in[5];
  const float* lemb = (const float*)d_in[6];
  const float* Wv = (const float*)d_in[7];   const float* bv = (const float*)d_in[8];
  const float* Wo = (const float*)d_in[9];   const float* bo = (const float*)d_in[10];
  const float* Wa = (const float*)d_in[11];  const float* ba = (const float*)d_in[12];
  const float* Wout = (const float*)d_in[13]; const float* bout = (const float*)d_in[14];
  const float* ln1g = (const float*)d_in[15]; const float* ln1b = (const float*)d_in[16];
  const float* W1 = (const float*)d_in[17];  const float* b1 = (const float*)d_in[18];
  const float* W2 = (const float*)d_in[19];  const float* b2 = (const float*)d_in[20];
  const float* ln2g = (const float*)d_in[21]; const float* ln2b = (const float*)d_in[22];

  const size_t M = M_TOK;
  const size_t SZ16 = 44040192ull;           // M*256*2
  const size_t POOL = 176160768ull;          // M*1024*2
  const size_t NEED = SZ16 + POOL + SZ16 + SZ16 + 8749056ull;   // 316.8 MB
  if (ws_size < NEED) return;

  char* ws = (char*)d_ws;
  unsigned short* slot0b = (unsigned short*)ws;   // 44 MB: value -> wout -> ff (serial reuse)
  unsigned short* valb = slot0b;
  unsigned short* woutb = slot0b;
  unsigned short* ffb = slot0b;
  char* pool = ws + SZ16;
  unsigned short* q_b16 = (unsigned short*)pool;
  unsigned short* oa_b16 = (unsigned short*)pool + M * 256;   // [M,288]: offs|aw
  unsigned short* attn_b16 = (unsigned short*)pool + M * 544;
  unsigned short* h_b16 = (unsigned short*)pool;  // clobbers q/oa/attn (dead by then)
  unsigned short* out_b16 = (unsigned short*)(pool + POOL);
  unsigned short* pos_b16 = out_b16 + M * 256;
  unsigned short* wt = pos_b16 + M * 256;

  unsigned short* wtv = wt;                 // [6][256][256]
  unsigned short* wtoa = wt + 393216;       // [6][288][256] (Wo rows 0..191, Wa 192..287)
  unsigned short* wtw = wt + 835584;        // [6][256][256]
  unsigned short* wt1 = wt + 1228800;       // [6][1024][256]
  unsigned short* wt2 = wt + 2801664;       // [6][256][1024]

  const dim3 b32(32, 8);
  wtrans_kernel<<<dim3(8, 8, 6), b32, 0, stream>>>(Wv, wtv, 256, 256, 65536, 65536);
  wtrans_kernel<<<dim3(6, 8, 6), b32, 0, stream>>>(Wo, wtoa, 256, 192, 49152, 73728);
  wtrans_kernel<<<dim3(3, 8, 6), b32, 0, stream>>>(Wa, wtoa + 192 * 256, 256, 96, 24576, 73728);
  wtrans_kernel<<<dim3(8, 8, 6), b32, 0, stream>>>(Wout, wtw, 256, 256, 65536, 65536);
  wtrans_kernel<<<dim3(32, 8, 6), b32, 0, stream>>>(W1, wt1, 256, 1024, 262144, 262144);
  wtrans_kernel<<<dim3(8, 32, 6), b32, 0, stream>>>(W2, wt2, 1024, 256, 262144, 262144);

  flatten_kernel<<<dim3(32, 8, 4), b32, 0, stream>>>(src0, pos0, lemb, out_b16, pos_b16, q_b16, 1024, 0);
  flatten_kernel<<<dim3(128, 8, 4), b32, 0, stream>>>(src1, pos1, lemb + 256, out_b16, pos_b16, q_b16, 4096, 1024);
  flatten_kernel<<<dim3(512, 8, 4), b32, 0, stream>>>(src2, pos2, lemb + 512, out_b16, pos_b16, q_b16, 16384, 5120);

  for (int l = 0; l < 6; l++) {
    gemm_kernel<0, 1><<<1344, 256, 0, stream>>>(out_b16, wtv + l * 65536, bv + l * 256, bv + l * 256, 256, valb, 256, 256, 2);
    gemm_kernel<0, 0><<<2016, 256, 0, stream>>>(q_b16, wtoa + l * 73728, bo + l * 192, ba + l * 96, 192, oa_b16, 288, 256, 3);
    deform_kernel<<<10752, 256, 0, stream>>>(valb, oa_b16, attn_b16);
    gemm_kernel<0, 0><<<1344, 256, 0, stream>>>(attn_b16, wtw + l * 65536, bout + l * 256, bout + l * 256, 256, woutb, 256, 256, 2);
    resln_kernel<<<21504, 256, 0, stream>>>(out_b16, woutb, ln1g + l * 256, ln1b + l * 256, out_b16, nullptr, nullptr, nullptr);
    gemm_kernel<1, 0><<<5376, 256, 0, stream>>>(out_b16, wt1 + l * 262144, b1 + l * 1024, b1 + l * 1024, 1024, h_b16, 1024, 256, 8);
    gemm_kernel<0, 0><<<1344, 256, 0, stream>>>(h_b16, wt2 + l * 262144, b2 + l * 256, b2 + l * 256, 256, ffb, 256, 1024, 2);
    if (l < 5) {
      resln_kernel<<<21504, 256, 0, stream>>>(out_b16, ffb, ln2g + l * 256, ln2b + l * 256, out_b16, pos_b16, q_b16, nullptr);
    } else {
      resln_kernel<<<21504, 256, 0, stream>>>(out_b16, ffb, ln2g + l * 256, ln2b + l * 256, nullptr, nullptr, nullptr, (float*)d_out);
    }
  }
}

// Round 24
// 2445.858 us; speedup vs baseline: 1.0848x; 1.0067x over previous
//
#include <hip/hip_runtime.h>
#include <hip/hip_fp16.h>
#include <stdint.h>

// ---------------- static problem config ----------------
#define S_TOT 21504
#define M_TOK 86016
// levels: (32,32) start 0, (64,64) start 1024, (128,128) start 5120

typedef __attribute__((ext_vector_type(8))) short bf16x8;
typedef __attribute__((ext_vector_type(4))) float f32x4;

__device__ __forceinline__ unsigned short f2b(float f) {
  union { float f; unsigned u; } v; v.f = f;
  unsigned r = v.u + 0x7FFFu + ((v.u >> 16) & 1u);
  return (unsigned short)(r >> 16);
}
__device__ __forceinline__ unsigned short f2h(float f) {
  __half h = __float2half(f);
  return __half_as_ushort(h);
}
__device__ __forceinline__ float b2f(unsigned short h) {
  union { unsigned u; float f; } v; v.u = ((unsigned)h) << 16;
  return v.f;
}
__device__ __forceinline__ float blo(unsigned u) {
  union { unsigned u; float f; } v; v.u = u << 16; return v.f;
}
__device__ __forceinline__ float bhi(unsigned u) {
  union { unsigned u; float f; } v; v.u = u & 0xffff0000u; return v.f;
}
// fp16 pair access; (float)h folds into v_fma_mix_f32 at the consuming fma
__device__ __forceinline__ float h2lo(unsigned u) {
  union { unsigned u; __half2 h; } v; v.u = u; return __half2float(v.h.x);
}
__device__ __forceinline__ float h2hi(unsigned u) {
  union { unsigned u; __half2 h; } v; v.u = u; return __half2float(v.h.y);
}

// global -> LDS direct DMA, 16B/lane; LDS dest = wave-uniform base + lane*16.
__device__ __forceinline__ void gload16(const unsigned short* g, unsigned short* l) {
  __builtin_amdgcn_global_load_lds(
      (const __attribute__((address_space(1))) unsigned int*)(const void*)g,
      (__attribute__((address_space(3))) unsigned int*)(void*)l, 16, 0, 0);
}

// ---------------- bf16 MFMA GEMM (round-23 form, best measured) ----------------
// BM=BN=128, 4 waves, XCD-swizzled 1D grid, double-buffered global_load_lds DMA
// (1 barrier/32-K), coalesced C via LDS bounce. OUTH=1 -> fp16 C (value).
#define TSZ 4096  // ushorts per 128x32 tile (8 KB)
template <int RELU, int OUTH>
__global__ __launch_bounds__(256) void gemm_kernel(
    const unsigned short* __restrict__ A, const unsigned short* __restrict__ Bt,
    const float* __restrict__ bias, const float* __restrict__ bias2, int nsplit,
    unsigned short* __restrict__ C, int N, int K, int ntx) {
  __shared__ unsigned short smem[4 * TSZ];  // [A0 | A1 | B0 | B1], 32 KB
  const int tid = threadIdx.x;
  const int wave = tid >> 6, lane = tid & 63;
  const int nblk = gridDim.x, chunk = nblk >> 3;
  const int bid = blockIdx.x;
  const int swz = (bid & 7) * chunk + (bid >> 3);
  const long m0 = (long)(swz / ntx) * 128;
  const int n0 = (swz % ntx) * 128;
  const int wm = (wave >> 1) * 64, wn = (wave & 1) * 64;

  f32x4 acc[4][4];
#pragma unroll
  for (int i = 0; i < 4; i++)
#pragma unroll
    for (int j = 0; j < 4; j++) acc[i][j] = (f32x4){0.f, 0.f, 0.f, 0.f};

  const int ar = tid >> 2, ak = (tid & 3) * 8;
  int brA = n0 + ar;      if (brA >= N) brA = N - 1;  // clamp OOB weight rows
  int brB = n0 + ar + 64; if (brB >= N) brB = N - 1;
  const unsigned short* a0p = A + (m0 + ar) * (long)K + ak;
  const unsigned short* a1p = A + (m0 + ar + 64) * (long)K + ak;
  const unsigned short* b0p = Bt + (long)brA * K + ak;
  const unsigned short* b1p = Bt + (long)brB * K + ak;
  const int wb = wave * 512;  // wave-uniform LDS base (ushorts); HW adds lane*16B

#define GEMM_STAGE(P, KOFF)                                        \
  {                                                                \
    gload16(a0p + (KOFF), smem + (P)*TSZ + wb);                    \
    gload16(a1p + (KOFF), smem + (P)*TSZ + 2048 + wb);             \
    gload16(b0p + (KOFF), smem + (2 + (P)) * TSZ + wb);            \
    gload16(b1p + (KOFF), smem + (2 + (P)) * TSZ + 2048 + wb);     \
  }

#define GEMM_COMPUTE(P)                                                               \
  {                                                                                   \
    const int kk = (lane >> 4) * 8;                                                   \
    const unsigned short* Ab = smem + (P)*TSZ;                                        \
    const unsigned short* Bb = smem + (2 + (P)) * TSZ;                                \
    bf16x8 af[4], bq[4];                                                              \
    _Pragma("unroll") for (int i = 0; i < 4; i++)                                     \
        af[i] = *(const bf16x8*)&Ab[(wm + i * 16 + (lane & 15)) * 32 + kk];           \
    _Pragma("unroll") for (int j = 0; j < 4; j++)                                     \
        bq[j] = *(const bf16x8*)&Bb[(wn + j * 16 + (lane & 15)) * 32 + kk];           \
    _Pragma("unroll") for (int i = 0; i < 4; i++)                                     \
        _Pragma("unroll") for (int j = 0; j < 4; j++)                                 \
            acc[i][j] = __builtin_amdgcn_mfma_f32_16x16x32_bf16(af[i], bq[j],         \
                                                                acc[i][j], 0, 0, 0); \
  }

  GEMM_STAGE(0, 0);
  __syncthreads();

  for (int k0 = 0; k0 < K; k0 += 64) {
    if (k0 + 32 < K) GEMM_STAGE(1, k0 + 32);
    GEMM_COMPUTE(0);
    __syncthreads();
    if (k0 + 64 < K) GEMM_STAGE(0, k0 + 64);
    GEMM_COMPUTE(1);
    __syncthreads();
  }
#undef GEMM_COMPUTE
#undef GEMM_STAGE

  // coalesced C-write via LDS bounce (64 rows x 136 stride)
  unsigned short* stage = smem;
  const int colb = lane & 15, rowb = (lane >> 4) * 4;
#pragma unroll
  for (int half = 0; half < 2; half++) {
    __syncthreads();
    if (wm == half * 64) {
#pragma unroll
      for (int j = 0; j < 4; j++) {
        const int n = n0 + wn + j * 16 + colb;
        const float bn = (n < N) ? ((n < nsplit) ? bias[n] : bias2[n - nsplit]) : 0.f;
#pragma unroll
        for (int i = 0; i < 4; i++) {
#pragma unroll
          for (int r = 0; r < 4; r++) {
            float v = acc[i][j][r] + bn;
            if (RELU) v = fmaxf(v, 0.f);
            stage[(i * 16 + rowb + r) * 136 + wn + j * 16 + colb] = OUTH ? f2h(v) : f2b(v);
          }
        }
      }
    }
    __syncthreads();
#pragma unroll
    for (int t = 0; t < 4; t++) {
      const int idx = t * 256 + tid;
      const int rr = idx >> 4;
      const int cc = (idx & 15) * 8;
      const int n = n0 + cc;
      if (n < N) {
        const long m = m0 + half * 64 + rr;
        *(uint4*)(C + m * N + n) = *(const uint4*)(stage + rr * 136 + cc);
      }
    }
  }
}

// ---------------- weight transpose + bf16 convert: [L][K][N] -> [L][N][K] ----------------
__global__ void wtrans_kernel(const float* __restrict__ src, unsigned short* __restrict__ dst,
                              int K, int N, size_t src_lstride, size_t dst_lstride) {
  __shared__ float t[32][33];
  const int tx = threadIdx.x, ty = threadIdx.y;
  const int n0 = blockIdx.x * 32, k0 = blockIdx.y * 32, l = blockIdx.z;
  src += (size_t)l * src_lstride;
  dst += (size_t)l * dst_lstride;
#pragma unroll
  for (int i = 0; i < 4; i++) t[ty * 4 + i][tx] = src[(size_t)(k0 + ty * 4 + i) * N + n0 + tx];
  __syncthreads();
#pragma unroll
  for (int i = 0; i < 4; i++)
    dst[(size_t)(n0 + ty * 4 + i) * K + k0 + tx] = f2b(t[tx][ty * 4 + i]);
}

// ---------------- flatten [B,C,H,W] -> [B,HW,C]; writes residual b16, pos b16, q b16 ----
__global__ void flatten_kernel(const float* __restrict__ src, const float* __restrict__ pos,
                               const float* __restrict__ lemb,
                               unsigned short* __restrict__ outb, unsigned short* __restrict__ posb,
                               unsigned short* __restrict__ qb, int HW, int s0) {
  __shared__ float ts[32][33];
  __shared__ float tp[32][33];
  const int tx = threadIdx.x, ty = threadIdx.y;
  const int hw0 = blockIdx.x * 32, c0 = blockIdx.y * 32, b = blockIdx.z;
  const size_t ibase = ((size_t)b * 256 + c0) * HW + hw0;
#pragma unroll
  for (int i = 0; i < 4; i++) {
    ts[ty * 4 + i][tx] = src[ibase + (size_t)(ty * 4 + i) * HW + tx];
    tp[ty * 4 + i][tx] = pos[ibase + (size_t)(ty * 4 + i) * HW + tx];
  }
  __syncthreads();
#pragma unroll
  for (int i = 0; i < 4; i++) {
    const int sI = s0 + hw0 + ty * 4 + i, c = c0 + tx;
    const size_t o = ((size_t)b * S_TOT + sI) * 256 + c;
    const float sv = ts[tx][ty * 4 + i];
    const unsigned short pb = f2b(tp[tx][ty * 4 + i] + lemb[c]);
    outb[o] = f2b(sv);
    posb[o] = pb;
    qb[o] = f2b(sv + b2f(pb));
  }
}

// ---------------- deformable attention sampling v6: 2 tokens/wave, fp16 dwt ----------
// LDS 27.6 KB -> 21.5 KB (dwt stored as fp16 pairs) => 7 blocks/CU (was 5), ~28 waves.
// Weights in [0,1]: fp16 mantissa (11b) finer than the bf16 data path; exact zeros kept.
// No barriers (law/didx/dwt slices are wave-private).
__global__ __launch_bounds__(256) void deform_kernel(const unsigned short* __restrict__ value,
                                                     const unsigned short* __restrict__ oa,
                                                     unsigned short* __restrict__ attn) {
  __shared__ float law[4][192];
  __shared__ uint4 didx[4][192];
  __shared__ __half2 dwt[4][192][2];   // (w.x,w.y),(w.z,w.w) as fp16 pairs
  const int tid = threadIdx.x;
  const int wv = tid >> 6, lane = tid & 63;
  const int tk = lane >> 5, sl = lane & 31;
  const int bs = blockIdx.x * 8 + wv * 2 + tk;
  const int b = bs / S_TOT, s = bs - b * S_TOT;

  if (sl < 8) {  // per-head softmax over NL*NP=12 (head = sl, token = tk)
    const unsigned short* ap = oa + (size_t)bs * 288 + 192 + sl * 12;
    const uint2 p0 = *(const uint2*)ap;
    const uint2 p1 = *(const uint2*)(ap + 4);
    const uint2 p2 = *(const uint2*)(ap + 8);
    float a[12] = {blo(p0.x), bhi(p0.x), blo(p0.y), bhi(p0.y),
                   blo(p1.x), bhi(p1.x), blo(p1.y), bhi(p1.y),
                   blo(p2.x), bhi(p2.x), blo(p2.y), bhi(p2.y)};
    float mx = a[0];
#pragma unroll
    for (int i = 1; i < 12; i++) mx = fmaxf(mx, a[i]);
    float e[12], sm = 0.f;
#pragma unroll
    for (int i = 0; i < 12; i++) { e[i] = __expf(a[i] - mx); sm += e[i]; }
    const float r = 1.f / sm;
#pragma unroll
    for (int i = 0; i < 12; i++) law[wv][tk * 96 + sl * 12 + i] = e[i] * r;
  }

  float rx, ry;
  {
    if (s < 1024) { const int li = s; rx = ((li & 31) + 0.5f) * (1.f / 32); ry = ((li >> 5) + 0.5f) * (1.f / 32); }
    else if (s < 5120) { const int li = s - 1024; rx = ((li & 63) + 0.5f) * (1.f / 64); ry = ((li >> 6) + 0.5f) * (1.f / 64); }
    else { const int li = s - 5120; rx = ((li & 127) + 0.5f) * (1.f / 128); ry = ((li >> 7) + 0.5f) * (1.f / 128); }
  }

  for (int ti = sl; ti < 96; ti += 32) {
    const int h = ti / 12;
    const int rem = ti - h * 12;
    const int lvl = rem >> 2;
    const int wl = 32 << lvl;
    const float fwl = (float)wl;
    const int start = (lvl == 0) ? 0 : ((lvl == 1) ? 1024 : 5120);
    const unsigned op = *(const unsigned*)(oa + (size_t)bs * 288 + 2 * ti);
    const float ox = blo(op), oy = bhi(op);
    const float x = (rx + ox / fwl) * fwl - 0.5f;   // matches ref FP order
    const float y = (ry + oy / fwl) * fwl - 0.5f;
    const float xf = floorf(x), yf = floorf(y);
    const int x0 = (int)xf, y0 = (int)yf;
    const float fx = x - xf, fy = y - yf;
    const bool xv0 = (x0 >= 0) & (x0 < wl), xv1 = (x0 + 1 >= 0) & (x0 + 1 < wl);
    const bool yv0 = (y0 >= 0) & (y0 < wl), yv1 = (y0 + 1 >= 0) & (y0 + 1 < wl);
    const int x0c = min(max(x0, 0), wl - 1), x1c = min(max(x0 + 1, 0), wl - 1);
    const int y0c = min(max(y0, 0), wl - 1), y1c = min(max(y0 + 1, 0), wl - 1);
    const float w = law[wv][tk * 96 + ti];
    const float w00 = (xv0 & yv0) ? w * (1.f - fx) * (1.f - fy) : 0.f;
    const float w01 = (xv1 & yv0) ? w * fx * (1.f - fy) : 0.f;
    const float w10 = (xv0 & yv1) ? w * (1.f - fx) * fy : 0.f;
    const float w11 = (xv1 & yv1) ? w * fx * fy : 0.f;
    const unsigned base = (unsigned)(((b * S_TOT + start) << 8) + h * 32) * 2u;
    uint4 iv;
    iv.x = base + (unsigned)(y0c * wl + x0c) * 512u;
    iv.y = base + (unsigned)(y0c * wl + x1c) * 512u;
    iv.z = base + (unsigned)(y1c * wl + x0c) * 512u;
    iv.w = base + (unsigned)(y1c * wl + x1c) * 512u;
    didx[wv][tk * 96 + ti] = iv;
    dwt[wv][tk * 96 + ti][0] = __floats2half2_rn(w00, w01);
    dwt[wv][tk * 96 + ti][1] = __floats2half2_rn(w10, w11);
  }

  const int h = sl >> 2, cg = sl & 3;
  const char* vb = (const char*)value + cg * 16;
  const uint4* ip = &didx[wv][tk * 96 + h * 12];
  const __half2 (*wp)[2] = &dwt[wv][tk * 96 + h * 12];
  float a0 = 0.f, a1 = 0.f, a2 = 0.f, a3 = 0.f;
  float a4 = 0.f, a5 = 0.f, a6 = 0.f, a7 = 0.f;
#pragma unroll
  for (int t = 0; t < 12; t++) {
    const uint4 iv = ip[t];
    const __half2 wA = wp[t][0], wB = wp[t][1];
    const float wx = __half2float(wA.x), wy = __half2float(wA.y);
    const float wz = __half2float(wB.x), ww = __half2float(wB.y);
    const uint4 q00 = *(const uint4*)(vb + iv.x);
    const uint4 q01 = *(const uint4*)(vb + iv.y);
    const uint4 q10 = *(const uint4*)(vb + iv.z);
    const uint4 q11 = *(const uint4*)(vb + iv.w);
    a0 += wx * h2lo(q00.x); a1 += wx * h2hi(q00.x);
    a2 += wx * h2lo(q00.y); a3 += wx * h2hi(q00.y);
    a4 += wx * h2lo(q00.z); a5 += wx * h2hi(q00.z);
    a6 += wx * h2lo(q00.w); a7 += wx * h2hi(q00.w);
    a0 += wy * h2lo(q01.x); a1 += wy * h2hi(q01.x);
    a2 += wy * h2lo(q01.y); a3 += wy * h2hi(q01.y);
    a4 += wy * h2lo(q01.z); a5 += wy * h2hi(q01.z);
    a6 += wy * h2lo(q01.w); a7 += wy * h2hi(q01.w);
    a0 += wz * h2lo(q10.x); a1 += wz * h2hi(q10.x);
    a2 += wz * h2lo(q10.y); a3 += wz * h2hi(q10.y);
    a4 += wz * h2lo(q10.z); a5 += wz * h2hi(q10.z);
    a6 += wz * h2lo(q10.w); a7 += wz * h2hi(q10.w);
    a0 += ww * h2lo(q11.x); a1 += ww * h2hi(q11.x);
    a2 += ww * h2lo(q11.y); a3 += ww * h2hi(q11.y);
    a4 += ww * h2lo(q11.z); a5 += ww * h2hi(q11.z);
    a6 += ww * h2lo(q11.w); a7 += ww * h2hi(q11.w);
  }
  uint4 o;
  o.x = (unsigned)f2b(a0) | ((unsigned)f2b(a1) << 16);
  o.y = (unsigned)f2b(a2) | ((unsigned)f2b(a3) << 16);
  o.z = (unsigned)f2b(a4) | ((unsigned)f2b(a5) << 16);
  o.w = (unsigned)f2b(a6) | ((unsigned)f2b(a7) << 16);
  *(uint4*)(attn + (size_t)bs * 256 + h * 32 + cg * 8) = o;
}

// ---------------- residual + layernorm; bf16 residual stream (in-place) ----------------
__global__ __launch_bounds__(256) void resln_kernel(const unsigned short* __restrict__ x,
                                                    const unsigned short* __restrict__ r,
                                                    const float* __restrict__ g,
                                                    const float* __restrict__ bta,
                                                    unsigned short* __restrict__ ob,
                                                    const unsigned short* __restrict__ pos,
                                                    unsigned short* __restrict__ qb,
                                                    float* __restrict__ fout) {
  const int t = blockIdx.x * 4 + (threadIdx.x >> 6);
  const int lane = threadIdx.x & 63;
  const size_t base = (size_t)t * 256;
  const ushort4 xv = ((const ushort4*)(x + base))[lane];
  const ushort4 rv = ((const ushort4*)(r + base))[lane];
  const float v0 = b2f(xv.x) + b2f(rv.x), v1 = b2f(xv.y) + b2f(rv.y);
  const float v2 = b2f(xv.z) + b2f(rv.z), v3 = b2f(xv.w) + b2f(rv.w);
  float sm = v0 + v1 + v2 + v3;
#pragma unroll
  for (int o = 32; o > 0; o >>= 1) sm += __shfl_xor(sm, o);
  const float mean = sm * (1.f / 256.f);
  const float d0 = v0 - mean, d1 = v1 - mean, d2 = v2 - mean, d3 = v3 - mean;
  float vs = d0 * d0 + d1 * d1 + d2 * d2 + d3 * d3;
#pragma unroll
  for (int o = 32; o > 0; o >>= 1) vs += __shfl_xor(vs, o);
  const float inv = rsqrtf(vs * (1.f / 256.f) + 1e-5f);
  const int c = lane * 4;
  const float o0 = d0 * inv * g[c] + bta[c];
  const float o1 = d1 * inv * g[c + 1] + bta[c + 1];
  const float o2 = d2 * inv * g[c + 2] + bta[c + 2];
  const float o3 = d3 * inv * g[c + 3] + bta[c + 3];
  if (fout) {
    ((float4*)(fout + base))[lane] = make_float4(o0, o1, o2, o3);
  } else {
    ushort4 u;
    u.x = f2b(o0); u.y = f2b(o1); u.z = f2b(o2); u.w = f2b(o3);
    ((ushort4*)(ob + base))[lane] = u;
  }
  if (qb) {
    const ushort4 pv = ((const ushort4*)(pos + base))[lane];
    ushort4 u;
    u.x = f2b(o0 + b2f(pv.x)); u.y = f2b(o1 + b2f(pv.y));
    u.z = f2b(o2 + b2f(pv.z)); u.w = f2b(o3 + b2f(pv.w));
    ((ushort4*)(qb + base))[lane] = u;
  }
}

// ---------------- host ----------------
extern "C" void kernel_launch(void* const* d_in, const int* in_sizes, int n_in,
                              void* d_out, int out_size, void* d_ws, size_t ws_size,
                              hipStream_t stream) {
  (void)in_sizes; (void)n_in; (void)out_size;
  const float* src0 = (const float*)d_in[0];
  const float* pos0 = (const float*)d_in[1];
  const float* src1 = (const float*)d_in[2];
  const float* pos1 = (const float*)d_in[3];
  const float* src2 = (const float*)d_in[4];
  const float* pos2 = (const float*)d_in[5];
  const float* lemb = (const float*)d_in[6];
  const float* Wv = (const float*)d_in[7];   const float* bv = (const float*)d_in[8];
  const float* Wo = (const float*)d_in[9];   const float* bo = (const float*)d_in[10];
  const float* Wa = (const float*)d_in[11];  const float* ba = (const float*)d_in[12];
  const float* Wout = (const float*)d_in[13]; const float* bout = (const float*)d_in[14];
  const float* ln1g = (const float*)d_in[15]; const float* ln1b = (const float*)d_in[16];
  const float* W1 = (const float*)d_in[17];  const float* b1 = (const float*)d_in[18];
  const float* W2 = (const float*)d_in[19];  const float* b2 = (const float*)d_in[20];
  const float* ln2g = (const float*)d_in[21]; const float* ln2b = (const float*)d_in[22];

  const size_t M = M_TOK;
  const size_t SZ16 = 44040192ull;           // M*256*2
  const size_t POOL = 176160768ull;          // M*1024*2
  const size_t NEED = SZ16 + POOL + SZ16 + SZ16 + 8749056ull;   // 316.8 MB
  if (ws_size < NEED) return;

  char* ws = (char*)d_ws;
  unsigned short* slot0b = (unsigned short*)ws;   // 44 MB: value -> wout -> ff (serial reuse)
  unsigned short* valb = slot0b;
  unsigned short* woutb = slot0b;
  unsigned short* ffb = slot0b;
  char* pool = ws + SZ16;
  unsigned short* q_b16 = (unsigned short*)pool;
  unsigned short* oa_b16 = (unsigned short*)pool + M * 256;   // [M,288]: offs|aw
  unsigned short* attn_b16 = (unsigned short*)pool + M * 544;
  unsigned short* h_b16 = (unsigned short*)pool;  // clobbers q/oa/attn (dead by then)
  unsigned short* out_b16 = (unsigned short*)(pool + POOL);
  unsigned short* pos_b16 = out_b16 + M * 256;
  unsigned short* wt = pos_b16 + M * 256;

  unsigned short* wtv = wt;                 // [6][256][256]
  unsigned short* wtoa = wt + 393216;       // [6][288][256] (Wo rows 0..191, Wa 192..287)
  unsigned short* wtw = wt + 835584;        // [6][256][256]
  unsigned short* wt1 = wt + 1228800;       // [6][1024][256]
  unsigned short* wt2 = wt + 2801664;       // [6][256][1024]

  const dim3 b32(32, 8);
  wtrans_kernel<<<dim3(8, 8, 6), b32, 0, stream>>>(Wv, wtv, 256, 256, 65536, 65536);
  wtrans_kernel<<<dim3(6, 8, 6), b32, 0, stream>>>(Wo, wtoa, 256, 192, 49152, 73728);
  wtrans_kernel<<<dim3(3, 8, 6), b32, 0, stream>>>(Wa, wtoa + 192 * 256, 256, 96, 24576, 73728);
  wtrans_kernel<<<dim3(8, 8, 6), b32, 0, stream>>>(Wout, wtw, 256, 256, 65536, 65536);
  wtrans_kernel<<<dim3(32, 8, 6), b32, 0, stream>>>(W1, wt1, 256, 1024, 262144, 262144);
  wtrans_kernel<<<dim3(8, 32, 6), b32, 0, stream>>>(W2, wt2, 1024, 256, 262144, 262144);

  flatten_kernel<<<dim3(32, 8, 4), b32, 0, stream>>>(src0, pos0, lemb, out_b16, pos_b16, q_b16, 1024, 0);
  flatten_kernel<<<dim3(128, 8, 4), b32, 0, stream>>>(src1, pos1, lemb + 256, out_b16, pos_b16, q_b16, 4096, 1024);
  flatten_kernel<<<dim3(512, 8, 4), b32, 0, stream>>>(src2, pos2, lemb + 512, out_b16, pos_b16, q_b16, 16384, 5120);

  for (int l = 0; l < 6; l++) {
    gemm_kernel<0, 1><<<1344, 256, 0, stream>>>(out_b16, wtv + l * 65536, bv + l * 256, bv + l * 256, 256, valb, 256, 256, 2);
    gemm_kernel<0, 0><<<2016, 256, 0, stream>>>(q_b16, wtoa + l * 73728, bo + l * 192, ba + l * 96, 192, oa_b16, 288, 256, 3);
    deform_kernel<<<10752, 256, 0, stream>>>(valb, oa_b16, attn_b16);
    gemm_kernel<0, 0><<<1344, 256, 0, stream>>>(attn_b16, wtw + l * 65536, bout + l * 256, bout + l * 256, 256, woutb, 256, 256, 2);
    resln_kernel<<<21504, 256, 0, stream>>>(out_b16, woutb, ln1g + l * 256, ln1b + l * 256, out_b16, nullptr, nullptr, nullptr);
    gemm_kernel<1, 0><<<5376, 256, 0, stream>>>(out_b16, wt1 + l * 262144, b1 + l * 1024, b1 + l * 1024, 1024, h_b16, 1024, 256, 8);
    gemm_kernel<0, 0><<<1344, 256, 0, stream>>>(h_b16, wt2 + l * 262144, b2 + l * 256, b2 + l * 256, 256, ffb, 256, 1024, 2);
    if (l < 5) {
      resln_kernel<<<21504, 256, 0, stream>>>(out_b16, ffb, ln2g + l * 256, ln2b + l * 256, out_b16, pos_b16, q_b16, nullptr);
    } else {
      resln_kernel<<<21504, 256, 0, stream>>>(out_b16, ffb, ln2g + l * 256, ln2b + l * 256, nullptr, nullptr, nullptr, (float*)d_out);
    }
  }
}

// Round 26
// 2389.260 us; speedup vs baseline: 1.1105x; 1.0237x over previous
//
#include <hip/hip_runtime.h>
#include <hip/hip_fp16.h>
#include <stdint.h>

// ---------------- static problem config ----------------
#define S_TOT 21504
#define M_TOK 86016
// levels: (32,32) start 0, (64,64) start 1024, (128,128) start 5120

typedef __attribute__((ext_vector_type(8))) short bf16x8;
typedef __attribute__((ext_vector_type(4))) float f32x4;

__device__ __forceinline__ unsigned short f2b(float f) {
  union { float f; unsigned u; } v; v.f = f;
  unsigned r = v.u + 0x7FFFu + ((v.u >> 16) & 1u);
  return (unsigned short)(r >> 16);
}
__device__ __forceinline__ unsigned short f2h(float f) {
  __half h = __float2half(f);
  return __half_as_ushort(h);
}
__device__ __forceinline__ float b2f(unsigned short h) {
  union { unsigned u; float f; } v; v.u = ((unsigned)h) << 16;
  return v.f;
}
__device__ __forceinline__ float blo(unsigned u) {
  union { unsigned u; float f; } v; v.u = u << 16; return v.f;
}
__device__ __forceinline__ float bhi(unsigned u) {
  union { unsigned u; float f; } v; v.u = u & 0xffff0000u; return v.f;
}
__device__ __forceinline__ float h2lo(unsigned u) {
  union { unsigned u; __half2 h; } v; v.u = u; return __half2float(v.h.x);
}
__device__ __forceinline__ float h2hi(unsigned u) {
  union { unsigned u; __half2 h; } v; v.u = u; return __half2float(v.h.y);
}

// global -> LDS direct DMA, 16B/lane; LDS dest = wave-uniform base + lane*16.
__device__ __forceinline__ void gload16(const unsigned short* g, unsigned short* l) {
  __builtin_amdgcn_global_load_lds(
      (const __attribute__((address_space(1))) unsigned int*)(const void*)g,
      (__attribute__((address_space(3))) unsigned int*)(void*)l, 16, 0, 0);
}

// ---------------- shared GEMM body (round-23 structure, runtime relu/outh) ----------
#define TSZ 4096  // ushorts per 128x32 tile (8 KB)
__device__ __forceinline__ void gemm_body(
    const unsigned short* __restrict__ A, const unsigned short* __restrict__ Bt,
    const float* __restrict__ bias, const float* __restrict__ bias2, int nsplit,
    unsigned short* __restrict__ C, int N, int K, int ntx,
    int bid, int nblk, int relu, int outh, unsigned short* smem) {
  const int tid = threadIdx.x;
  const int wave = tid >> 6, lane = tid & 63;
  const int chunk = nblk >> 3;
  const int swz = (bid & 7) * chunk + (bid >> 3);
  const long m0 = (long)(swz / ntx) * 128;
  const int n0 = (swz % ntx) * 128;
  const int wm = (wave >> 1) * 64, wn = (wave & 1) * 64;

  f32x4 acc[4][4];
#pragma unroll
  for (int i = 0; i < 4; i++)
#pragma unroll
    for (int j = 0; j < 4; j++) acc[i][j] = (f32x4){0.f, 0.f, 0.f, 0.f};

  const int ar = tid >> 2, ak = (tid & 3) * 8;
  int brA = n0 + ar;      if (brA >= N) brA = N - 1;  // clamp OOB weight rows
  int brB = n0 + ar + 64; if (brB >= N) brB = N - 1;
  const unsigned short* a0p = A + (m0 + ar) * (long)K + ak;
  const unsigned short* a1p = A + (m0 + ar + 64) * (long)K + ak;
  const unsigned short* b0p = Bt + (long)brA * K + ak;
  const unsigned short* b1p = Bt + (long)brB * K + ak;
  const int wb = wave * 512;  // wave-uniform LDS base (ushorts); HW adds lane*16B

#define GEMM_STAGE(P, KOFF)                                        \
  {                                                                \
    gload16(a0p + (KOFF), smem + (P)*TSZ + wb);                    \
    gload16(a1p + (KOFF), smem + (P)*TSZ + 2048 + wb);             \
    gload16(b0p + (KOFF), smem + (2 + (P)) * TSZ + wb);            \
    gload16(b1p + (KOFF), smem + (2 + (P)) * TSZ + 2048 + wb);     \
  }

#define GEMM_COMPUTE(P)                                                               \
  {                                                                                   \
    const int kk = (lane >> 4) * 8;                                                   \
    const unsigned short* Ab = smem + (P)*TSZ;                                        \
    const unsigned short* Bb = smem + (2 + (P)) * TSZ;                                \
    bf16x8 af[4], bq[4];                                                              \
    _Pragma("unroll") for (int i = 0; i < 4; i++)                                     \
        af[i] = *(const bf16x8*)&Ab[(wm + i * 16 + (lane & 15)) * 32 + kk];           \
    _Pragma("unroll") for (int j = 0; j < 4; j++)                                     \
        bq[j] = *(const bf16x8*)&Bb[(wn + j * 16 + (lane & 15)) * 32 + kk];           \
    _Pragma("unroll") for (int i = 0; i < 4; i++)                                     \
        _Pragma("unroll") for (int j = 0; j < 4; j++)                                 \
            acc[i][j] = __builtin_amdgcn_mfma_f32_16x16x32_bf16(af[i], bq[j],         \
                                                                acc[i][j], 0, 0, 0); \
  }

  GEMM_STAGE(0, 0);
  __syncthreads();

  for (int k0 = 0; k0 < K; k0 += 64) {
    if (k0 + 32 < K) GEMM_STAGE(1, k0 + 32);
    GEMM_COMPUTE(0);
    __syncthreads();
    if (k0 + 64 < K) GEMM_STAGE(0, k0 + 64);
    GEMM_COMPUTE(1);
    __syncthreads();
  }
#undef GEMM_COMPUTE
#undef GEMM_STAGE

  // coalesced C-write via LDS bounce (64 rows x 136 stride)
  unsigned short* stage = smem;
  const int colb = lane & 15, rowb = (lane >> 4) * 4;
#pragma unroll
  for (int half = 0; half < 2; half++) {
    __syncthreads();
    if (wm == half * 64) {
#pragma unroll
      for (int j = 0; j < 4; j++) {
        const int n = n0 + wn + j * 16 + colb;
        const float bn = (n < N) ? ((n < nsplit) ? bias[n] : bias2[n - nsplit]) : 0.f;
#pragma unroll
        for (int i = 0; i < 4; i++) {
#pragma unroll
          for (int r = 0; r < 4; r++) {
            float v = acc[i][j][r] + bn;
            if (relu) v = fmaxf(v, 0.f);
            stage[(i * 16 + rowb + r) * 136 + wn + j * 16 + colb] = outh ? f2h(v) : f2b(v);
          }
        }
      }
    }
    __syncthreads();
#pragma unroll
    for (int t = 0; t < 4; t++) {
      const int idx = t * 256 + tid;
      const int rr = idx >> 4;
      const int cc = (idx & 15) * 8;
      const int n = n0 + cc;
      if (n < N) {
        const long m = m0 + half * 64 + rr;
        *(uint4*)(C + m * N + n) = *(const uint4*)(stage + rr * 136 + cc);
      }
    }
  }
}

// standard single GEMM entry
template <int RELU, int OUTH>
__global__ __launch_bounds__(256) void gemm_kernel(
    const unsigned short* __restrict__ A, const unsigned short* __restrict__ Bt,
    const float* __restrict__ bias, const float* __restrict__ bias2, int nsplit,
    unsigned short* __restrict__ C, int N, int K, int ntx) {
  __shared__ unsigned short smem[4 * TSZ];
  gemm_body(A, Bt, bias, bias2, nsplit, C, N, K, ntx,
            blockIdx.x, gridDim.x, RELU, OUTH, smem);
}

// dual GEMM entry: blocks [0,nblk1) run GEMM-1 (outh=1), the rest run GEMM-2.
// nblk1 MUST equal (M/128)*ntx1; total grid = nblk1 + (M/128)*ntx2. Both segments
// independent (inputs produced by the same preceding kernel) -> tail overlap.
__global__ __launch_bounds__(256) void gemm_dual_kernel(
    const unsigned short* __restrict__ A1, const unsigned short* __restrict__ Bt1,
    const float* __restrict__ bias1, unsigned short* __restrict__ C1, int N1, int ntx1, int nblk1,
    const unsigned short* __restrict__ A2, const unsigned short* __restrict__ Bt2,
    const float* __restrict__ bias2a, const float* __restrict__ bias2b, int nsplit2,
    unsigned short* __restrict__ C2, int N2, int ntx2, int K) {
  __shared__ unsigned short smem[4 * TSZ];
  const int bid = blockIdx.x;
  if (bid < nblk1) {
    gemm_body(A1, Bt1, bias1, bias1, N1, C1, N1, K, ntx1, bid, nblk1, 0, 1, smem);
  } else {
    gemm_body(A2, Bt2, bias2a, bias2b, nsplit2, C2, N2, K, ntx2,
              bid - nblk1, gridDim.x - nblk1, 0, 0, smem);
  }
}

// ---------------- weight transpose + bf16 convert: [L][K][N] -> [L][N][K] ----------------
__global__ void wtrans_kernel(const float* __restrict__ src, unsigned short* __restrict__ dst,
                              int K, int N, size_t src_lstride, size_t dst_lstride) {
  __shared__ float t[32][33];
  const int tx = threadIdx.x, ty = threadIdx.y;
  const int n0 = blockIdx.x * 32, k0 = blockIdx.y * 32, l = blockIdx.z;
  src += (size_t)l * src_lstride;
  dst += (size_t)l * dst_lstride;
#pragma unroll
  for (int i = 0; i < 4; i++) t[ty * 4 + i][tx] = src[(size_t)(k0 + ty * 4 + i) * N + n0 + tx];
  __syncthreads();
#pragma unroll
  for (int i = 0; i < 4; i++)
    dst[(size_t)(n0 + ty * 4 + i) * K + k0 + tx] = f2b(t[tx][ty * 4 + i]);
}

// ---------------- flatten [B,C,H,W] -> [B,HW,C]; writes residual b16, pos b16, q b16 ----
__global__ void flatten_kernel(const float* __restrict__ src, const float* __restrict__ pos,
                               const float* __restrict__ lemb,
                               unsigned short* __restrict__ outb, unsigned short* __restrict__ posb,
                               unsigned short* __restrict__ qb, int HW, int s0) {
  __shared__ float ts[32][33];
  __shared__ float tp[32][33];
  const int tx = threadIdx.x, ty = threadIdx.y;
  const int hw0 = blockIdx.x * 32, c0 = blockIdx.y * 32, b = blockIdx.z;
  const size_t ibase = ((size_t)b * 256 + c0) * HW + hw0;
#pragma unroll
  for (int i = 0; i < 4; i++) {
    ts[ty * 4 + i][tx] = src[ibase + (size_t)(ty * 4 + i) * HW + tx];
    tp[ty * 4 + i][tx] = pos[ibase + (size_t)(ty * 4 + i) * HW + tx];
  }
  __syncthreads();
#pragma unroll
  for (int i = 0; i < 4; i++) {
    const int sI = s0 + hw0 + ty * 4 + i, c = c0 + tx;
    const size_t o = ((size_t)b * S_TOT + sI) * 256 + c;
    const float sv = ts[tx][ty * 4 + i];
    const unsigned short pb = f2b(tp[tx][ty * 4 + i] + lemb[c]);
    outb[o] = f2b(sv);
    posb[o] = pb;
    qb[o] = f2b(sv + b2f(pb));
  }
}

// ---------------- deformable attention sampling v6 (round-24, best measured) ----------
__global__ __launch_bounds__(256) void deform_kernel(const unsigned short* __restrict__ value,
                                                     const unsigned short* __restrict__ oa,
                                                     unsigned short* __restrict__ attn) {
  __shared__ float law[4][192];
  __shared__ uint4 didx[4][192];
  __shared__ __half2 dwt[4][192][2];
  const int tid = threadIdx.x;
  const int wv = tid >> 6, lane = tid & 63;
  const int tk = lane >> 5, sl = lane & 31;
  const int bs = blockIdx.x * 8 + wv * 2 + tk;
  const int b = bs / S_TOT, s = bs - b * S_TOT;

  if (sl < 8) {
    const unsigned short* ap = oa + (size_t)bs * 288 + 192 + sl * 12;
    const uint2 p0 = *(const uint2*)ap;
    const uint2 p1 = *(const uint2*)(ap + 4);
    const uint2 p2 = *(const uint2*)(ap + 8);
    float a[12] = {blo(p0.x), bhi(p0.x), blo(p0.y), bhi(p0.y),
                   blo(p1.x), bhi(p1.x), blo(p1.y), bhi(p1.y),
                   blo(p2.x), bhi(p2.x), blo(p2.y), bhi(p2.y)};
    float mx = a[0];
#pragma unroll
    for (int i = 1; i < 12; i++) mx = fmaxf(mx, a[i]);
    float e[12], sm = 0.f;
#pragma unroll
    for (int i = 0; i < 12; i++) { e[i] = __expf(a[i] - mx); sm += e[i]; }
    const float r = 1.f / sm;
#pragma unroll
    for (int i = 0; i < 12; i++) law[wv][tk * 96 + sl * 12 + i] = e[i] * r;
  }

  float rx, ry;
  {
    if (s < 1024) { const int li = s; rx = ((li & 31) + 0.5f) * (1.f / 32); ry = ((li >> 5) + 0.5f) * (1.f / 32); }
    else if (s < 5120) { const int li = s - 1024; rx = ((li & 63) + 0.5f) * (1.f / 64); ry = ((li >> 6) + 0.5f) * (1.f / 64); }
    else { const int li = s - 5120; rx = ((li & 127) + 0.5f) * (1.f / 128); ry = ((li >> 7) + 0.5f) * (1.f / 128); }
  }

  for (int ti = sl; ti < 96; ti += 32) {
    const int h = ti / 12;
    const int rem = ti - h * 12;
    const int lvl = rem >> 2;
    const int wl = 32 << lvl;
    const float fwl = (float)wl;
    const int start = (lvl == 0) ? 0 : ((lvl == 1) ? 1024 : 5120);
    const unsigned op = *(const unsigned*)(oa + (size_t)bs * 288 + 2 * ti);
    const float ox = blo(op), oy = bhi(op);
    const float x = (rx + ox / fwl) * fwl - 0.5f;   // matches ref FP order
    const float y = (ry + oy / fwl) * fwl - 0.5f;
    const float xf = floorf(x), yf = floorf(y);
    const int x0 = (int)xf, y0 = (int)yf;
    const float fx = x - xf, fy = y - yf;
    const bool xv0 = (x0 >= 0) & (x0 < wl), xv1 = (x0 + 1 >= 0) & (x0 + 1 < wl);
    const bool yv0 = (y0 >= 0) & (y0 < wl), yv1 = (y0 + 1 >= 0) & (y0 + 1 < wl);
    const int x0c = min(max(x0, 0), wl - 1), x1c = min(max(x0 + 1, 0), wl - 1);
    const int y0c = min(max(y0, 0), wl - 1), y1c = min(max(y0 + 1, 0), wl - 1);
    const float w = law[wv][tk * 96 + ti];
    const float w00 = (xv0 & yv0) ? w * (1.f - fx) * (1.f - fy) : 0.f;
    const float w01 = (xv1 & yv0) ? w * fx * (1.f - fy) : 0.f;
    const float w10 = (xv0 & yv1) ? w * (1.f - fx) * fy : 0.f;
    const float w11 = (xv1 & yv1) ? w * fx * fy : 0.f;
    const unsigned base = (unsigned)(((b * S_TOT + start) << 8) + h * 32) * 2u;
    uint4 iv;
    iv.x = base + (unsigned)(y0c * wl + x0c) * 512u;
    iv.y = base + (unsigned)(y0c * wl + x1c) * 512u;
    iv.z = base + (unsigned)(y1c * wl + x0c) * 512u;
    iv.w = base + (unsigned)(y1c * wl + x1c) * 512u;
    didx[wv][tk * 96 + ti] = iv;
    dwt[wv][tk * 96 + ti][0] = __floats2half2_rn(w00, w01);
    dwt[wv][tk * 96 + ti][1] = __floats2half2_rn(w10, w11);
  }

  const int h = sl >> 2, cg = sl & 3;
  const char* vb = (const char*)value + cg * 16;
  const uint4* ip = &didx[wv][tk * 96 + h * 12];
  const __half2 (*wp)[2] = &dwt[wv][tk * 96 + h * 12];
  float a0 = 0.f, a1 = 0.f, a2 = 0.f, a3 = 0.f;
  float a4 = 0.f, a5 = 0.f, a6 = 0.f, a7 = 0.f;
#pragma unroll
  for (int t = 0; t < 12; t++) {
    const uint4 iv = ip[t];
    const __half2 wA = wp[t][0], wB = wp[t][1];
    const float wx = __half2float(wA.x), wy = __half2float(wA.y);
    const float wz = __half2float(wB.x), ww = __half2float(wB.y);
    const uint4 q00 = *(const uint4*)(vb + iv.x);
    const uint4 q01 = *(const uint4*)(vb + iv.y);
    const uint4 q10 = *(const uint4*)(vb + iv.z);
    const uint4 q11 = *(const uint4*)(vb + iv.w);
    a0 += wx * h2lo(q00.x); a1 += wx * h2hi(q00.x);
    a2 += wx * h2lo(q00.y); a3 += wx * h2hi(q00.y);
    a4 += wx * h2lo(q00.z); a5 += wx * h2hi(q00.z);
    a6 += wx * h2lo(q00.w); a7 += wx * h2hi(q00.w);
    a0 += wy * h2lo(q01.x); a1 += wy * h2hi(q01.x);
    a2 += wy * h2lo(q01.y); a3 += wy * h2hi(q01.y);
    a4 += wy * h2lo(q01.z); a5 += wy * h2hi(q01.z);
    a6 += wy * h2lo(q01.w); a7 += wy * h2hi(q01.w);
    a0 += wz * h2lo(q10.x); a1 += wz * h2hi(q10.x);
    a2 += wz * h2lo(q10.y); a3 += wz * h2hi(q10.y);
    a4 += wz * h2lo(q10.z); a5 += wz * h2hi(q10.z);
    a6 += wz * h2lo(q10.w); a7 += wz * h2hi(q10.w);
    a0 += ww * h2lo(q11.x); a1 += ww * h2hi(q11.x);
    a2 += ww * h2lo(q11.y); a3 += ww * h2hi(q11.y);
    a4 += ww * h2lo(q11.z); a5 += ww * h2hi(q11.z);
    a6 += ww * h2lo(q11.w); a7 += ww * h2hi(q11.w);
  }
  uint4 o;
  o.x = (unsigned)f2b(a0) | ((unsigned)f2b(a1) << 16);
  o.y = (unsigned)f2b(a2) | ((unsigned)f2b(a3) << 16);
  o.z = (unsigned)f2b(a4) | ((unsigned)f2b(a5) << 16);
  o.w = (unsigned)f2b(a6) | ((unsigned)f2b(a7) << 16);
  *(uint4*)(attn + (size_t)bs * 256 + h * 32 + cg * 8) = o;
}

// ---------------- residual + layernorm; bf16 residual stream (in-place) ----------------
__global__ __launch_bounds__(256) void resln_kernel(const unsigned short* __restrict__ x,
                                                    const unsigned short* __restrict__ r,
                                                    const float* __restrict__ g,
                                                    const float* __restrict__ bta,
                                                    unsigned short* __restrict__ ob,
                                                    const unsigned short* __restrict__ pos,
                                                    unsigned short* __restrict__ qb,
                                                    float* __restrict__ fout) {
  const int t = blockIdx.x * 4 + (threadIdx.x >> 6);
  const int lane = threadIdx.x & 63;
  const size_t base = (size_t)t * 256;
  const ushort4 xv = ((const ushort4*)(x + base))[lane];
  const ushort4 rv = ((const ushort4*)(r + base))[lane];
  const float v0 = b2f(xv.x) + b2f(rv.x), v1 = b2f(xv.y) + b2f(rv.y);
  const float v2 = b2f(xv.z) + b2f(rv.z), v3 = b2f(xv.w) + b2f(rv.w);
  float sm = v0 + v1 + v2 + v3;
#pragma unroll
  for (int o = 32; o > 0; o >>= 1) sm += __shfl_xor(sm, o);
  const float mean = sm * (1.f / 256.f);
  const float d0 = v0 - mean, d1 = v1 - mean, d2 = v2 - mean, d3 = v3 - mean;
  float vs = d0 * d0 + d1 * d1 + d2 * d2 + d3 * d3;
#pragma unroll
  for (int o = 32; o > 0; o >>= 1) vs += __shfl_xor(vs, o);
  const float inv = rsqrtf(vs * (1.f / 256.f) + 1e-5f);
  const int c = lane * 4;
  const float o0 = d0 * inv * g[c] + bta[c];
  const float o1 = d1 * inv * g[c + 1] + bta[c + 1];
  const float o2 = d2 * inv * g[c + 2] + bta[c + 2];
  const float o3 = d3 * inv * g[c + 3] + bta[c + 3];
  if (fout) {
    ((float4*)(fout + base))[lane] = make_float4(o0, o1, o2, o3);
  } else {
    ushort4 u;
    u.x = f2b(o0); u.y = f2b(o1); u.z = f2b(o2); u.w = f2b(o3);
    ((ushort4*)(ob + base))[lane] = u;
  }
  if (qb) {
    const ushort4 pv = ((const ushort4*)(pos + base))[lane];
    ushort4 u;
    u.x = f2b(o0 + b2f(pv.x)); u.y = f2b(o1 + b2f(pv.y));
    u.z = f2b(o2 + b2f(pv.z)); u.w = f2b(o3 + b2f(pv.w));
    ((ushort4*)(qb + base))[lane] = u;
  }
}

// ---------------- host ----------------
extern "C" void kernel_launch(void* const* d_in, const int* in_sizes, int n_in,
                              void* d_out, int out_size, void* d_ws, size_t ws_size,
                              hipStream_t stream) {
  (void)in_sizes; (void)n_in; (void)out_size;
  const float* src0 = (const float*)d_in[0];
  const float* pos0 = (const float*)d_in[1];
  const float* src1 = (const float*)d_in[2];
  const float* pos1 = (const float*)d_in[3];
  const float* src2 = (const float*)d_in[4];
  const float* pos2 = (const float*)d_in[5];
  const float* lemb = (const float*)d_in[6];
  const float* Wv = (const float*)d_in[7];   const float* bv = (const float*)d_in[8];
  const float* Wo = (const float*)d_in[9];   const float* bo = (const float*)d_in[10];
  const float* Wa = (const float*)d_in[11];  const float* ba = (const float*)d_in[12];
  const float* Wout = (const float*)d_in[13]; const float* bout = (const float*)d_in[14];
  const float* ln1g = (const float*)d_in[15]; const float* ln1b = (const float*)d_in[16];
  const float* W1 = (const float*)d_in[17];  const float* b1 = (const float*)d_in[18];
  const float* W2 = (const float*)d_in[19];  const float* b2 = (const float*)d_in[20];
  const float* ln2g = (const float*)d_in[21]; const float* ln2b = (const float*)d_in[22];

  const size_t M = M_TOK;
  const size_t SZ16 = 44040192ull;           // M*256*2
  const size_t POOL = 176160768ull;          // M*1024*2
  const size_t NEED = SZ16 + POOL + SZ16 + SZ16 + 8749056ull;   // 316.8 MB
  if (ws_size < NEED) return;

  char* ws = (char*)d_ws;
  unsigned short* slot0b = (unsigned short*)ws;   // 44 MB: value -> wout -> ff (serial reuse)
  unsigned short* valb = slot0b;
  unsigned short* woutb = slot0b;
  unsigned short* ffb = slot0b;
  char* pool = ws + SZ16;
  unsigned short* q_b16 = (unsigned short*)pool;
  unsigned short* oa_b16 = (unsigned short*)pool + M * 256;   // [M,288]: offs|aw
  unsigned short* attn_b16 = (unsigned short*)pool + M * 544;
  unsigned short* h_b16 = (unsigned short*)pool;  // clobbers q/oa/attn (dead by then)
  unsigned short* out_b16 = (unsigned short*)(pool + POOL);
  unsigned short* pos_b16 = out_b16 + M * 256;
  unsigned short* wt = pos_b16 + M * 256;

  unsigned short* wtv = wt;                 // [6][256][256]
  unsigned short* wtoa = wt + 393216;       // [6][288][256] (Wo rows 0..191, Wa 192..287)
  unsigned short* wtw = wt + 835584;        // [6][256][256]
  unsigned short* wt1 = wt + 1228800;       // [6][1024][256]
  unsigned short* wt2 = wt + 2801664;       // [6][256][1024]

  const dim3 b32(32, 8);
  wtrans_kernel<<<dim3(8, 8, 6), b32, 0, stream>>>(Wv, wtv, 256, 256, 65536, 65536);
  wtrans_kernel<<<dim3(6, 8, 6), b32, 0, stream>>>(Wo, wtoa, 256, 192, 49152, 73728);
  wtrans_kernel<<<dim3(3, 8, 6), b32, 0, stream>>>(Wa, wtoa + 192 * 256, 256, 96, 24576, 73728);
  wtrans_kernel<<<dim3(8, 8, 6), b32, 0, stream>>>(Wout, wtw, 256, 256, 65536, 65536);
  wtrans_kernel<<<dim3(32, 8, 6), b32, 0, stream>>>(W1, wt1, 256, 1024, 262144, 262144);
  wtrans_kernel<<<dim3(8, 32, 6), b32, 0, stream>>>(W2, wt2, 1024, 256, 262144, 262144);

  flatten_kernel<<<dim3(32, 8, 4), b32, 0, stream>>>(src0, pos0, lemb, out_b16, pos_b16, q_b16, 1024, 0);
  flatten_kernel<<<dim3(128, 8, 4), b32, 0, stream>>>(src1, pos1, lemb + 256, out_b16, pos_b16, q_b16, 4096, 1024);
  flatten_kernel<<<dim3(512, 8, 4), b32, 0, stream>>>(src2, pos2, lemb + 512, out_b16, pos_b16, q_b16, 16384, 5120);

  for (int l = 0; l < 6; l++) {
    // merged Wv (fp16 value out, 672*2=1344 blocks) + Wo|Wa (bf16 oa out, 672*3=2016):
    // independent inputs -> tails overlap; total grid 3360.
    gemm_dual_kernel<<<3360, 256, 0, stream>>>(
        out_b16, wtv + l * 65536, bv + l * 256, valb, 256, 2, 1344,
        q_b16, wtoa + l * 73728, bo + l * 192, ba + l * 96, 192, oa_b16, 288, 3, 256);
    deform_kernel<<<10752, 256, 0, stream>>>(valb, oa_b16, attn_b16);
    gemm_kernel<0, 0><<<1344, 256, 0, stream>>>(attn_b16, wtw + l * 65536, bout + l * 256, bout + l * 256, 256, woutb, 256, 256, 2);
    resln_kernel<<<21504, 256, 0, stream>>>(out_b16, woutb, ln1g + l * 256, ln1b + l * 256, out_b16, nullptr, nullptr, nullptr);
    gemm_kernel<1, 0><<<5376, 256, 0, stream>>>(out_b16, wt1 + l * 262144, b1 + l * 1024, b1 + l * 1024, 1024, h_b16, 1024, 256, 8);
    gemm_kernel<0, 0><<<1344, 256, 0, stream>>>(h_b16, wt2 + l * 262144, b2 + l * 256, b2 + l * 256, 256, ffb, 256, 1024, 2);
    if (l < 5) {
      resln_kernel<<<21504, 256, 0, stream>>>(out_b16, ffb, ln2g + l * 256, ln2b + l * 256, out_b16, pos_b16, q_b16, nullptr);
    } else {
      resln_kernel<<<21504, 256, 0, stream>>>(out_b16, ffb, ln2g + l * 256, ln2b + l * 256, nullptr, nullptr, nullptr, (float*)d_out);
    }
  }
}